// Round 1
// baseline (1872.256 us; speedup 1.0000x reference)
//
#include <hip/hip_runtime.h>

// ---------------- config ----------------
#define CAP 64          // per-node incoming-edge bucket capacity (max in-degree ~40)
#define GB  64          // batch (number of graphs)
#define F   128         // GCN hidden dim
#define FC1K 18640
#define FC1CH 128       // k-chunks for fc1
#define FC1CS 146       // ceil(18640/128)

static inline int cdiv(long a, long b){ return (int)((a + b - 1) / b); }

// ---------------- graph build ----------------
__global__ void k_bucket_fill(const int* __restrict__ ei, int E,
                              int* __restrict__ cnt, int* __restrict__ idx) {
  int e = blockIdx.x * blockDim.x + threadIdx.x;
  if (e >= E) return;
  int s = ei[e], d = ei[E + e];
  int c = atomicAdd(&cnt[d], 1);
  if (c < CAP) idx[d * CAP + c] = s;
}

__global__ void k_dinv(const int* __restrict__ cnt, float* __restrict__ dinv, int n) {
  int i = blockIdx.x * blockDim.x + threadIdx.x;
  if (i < n) dinv[i] = rsqrtf((float)cnt[i] + 1.0f);   // +1 self loop; deg >= 1
}

// ---------------- node linear layers ----------------
// x[n,9] @ W[9,128] -> h[n,128]
__global__ void k_lin9(const float* __restrict__ x, const float* __restrict__ W,
                       float* __restrict__ h, int n) {
  int t = blockIdx.x * blockDim.x + threadIdx.x;
  int v = t >> 7, j = t & 127;
  if (v >= n) return;
  float acc = 0.f;
  #pragma unroll
  for (int k = 0; k < 9; k++) acc += x[v * 9 + k] * W[k * 128 + j];
  h[v * 128 + j] = acc;
}

// h[n,128] @ W[128,128] -> out[n,128]; 16 nodes per 256-thread block
__global__ void k_lin128(const float* __restrict__ hin, const float* __restrict__ W,
                         float* __restrict__ hout, int n) {
  __shared__ float rows[16][128];
  int base = blockIdx.x * 16;
  int tid = threadIdx.x;
  for (int t = tid; t < 16 * 128; t += 256) {
    int v = base + (t >> 7);
    rows[t >> 7][t & 127] = (v < n) ? hin[v * 128 + (t & 127)] : 0.f;
  }
  __syncthreads();
  int j = tid & 127, s = tid >> 7;     // s in {0,1}
  float acc[8] = {0,0,0,0,0,0,0,0};
  for (int k = 0; k < 128; k++) {
    float w = W[k * 128 + j];
    #pragma unroll
    for (int r = 0; r < 8; r++) acc[r] += rows[s + 2 * r][k] * w;  // LDS broadcast
  }
  #pragma unroll
  for (int r = 0; r < 8; r++) {
    int v = base + s + 2 * r;
    if (v < n) hout[v * 128 + j] = acc[r];
  }
}

// ---------------- GCN aggregation (gather) + bias + relu ----------------
// out[v] = relu( dinv[v] * ( sum_{s in N(v)} dinv[s]*h[s] + dinv[v]*h[v] ) + b )
__global__ void k_gather(const float* __restrict__ h, const float* __restrict__ dinv,
                         const int* __restrict__ cnt, const int* __restrict__ idx,
                         const float* __restrict__ bias, float* __restrict__ out, int n) {
  int v = blockIdx.x;
  if (v >= n) return;
  int f = threadIdx.x;
  float dv = dinv[v];
  int deg = cnt[v]; if (deg > CAP) deg = CAP;
  float acc = dv * h[v * 128 + f];
  for (int p = 0; p < deg; p++) {
    int s = idx[v * CAP + p];
    acc += dinv[s] * h[s * 128 + f];
  }
  out[v * 128 + f] = fmaxf(dv * acc + bias[f], 0.f);
}

// ---------------- mean pool (batch vector is sorted) ----------------
__global__ void k_pool(const float* __restrict__ h, const int* __restrict__ batch,
                       float* __restrict__ sums, int n, int npb) {
  int f = threadIdx.x;
  long v0 = (long)blockIdx.x * npb;
  if (v0 >= n) return;
  long v1 = v0 + npb; if (v1 > n) v1 = n;
  int cur = batch[v0];
  float acc = 0.f;
  for (long v = v0; v < v1; ++v) {
    int bv = batch[v];
    if (bv != cur) { atomicAdd(&sums[cur * 128 + f], acc); acc = 0.f; cur = bv; }
    acc += h[v * 128 + f];
  }
  atomicAdd(&sums[cur * 128 + f], acc);
}

__global__ void k_count(const int* __restrict__ batch, float* __restrict__ cnt, int n) {
  int i = blockIdx.x * blockDim.x + threadIdx.x;
  if (i < n) atomicAdd(&cnt[batch[i]], 1.f);
}

__global__ void k_pool_div(float* __restrict__ sums, const float* __restrict__ cnt, int total) {
  int i = blockIdx.x * blockDim.x + threadIdx.x;
  if (i < total) sums[i] /= fmaxf(cnt[i >> 7], 1.f);
}

// ---------------- fc1: [64,18640]@[18640,128], k-chunked ----------------
__global__ void k_fc1_part(const float* __restrict__ md, const float* __restrict__ W,
                           float* __restrict__ part) {
  int c = blockIdx.x, j = threadIdx.x;
  int k0 = c * FC1CS, k1 = k0 + FC1CS; if (k1 > FC1K) k1 = FC1K;
  float acc[GB];
  #pragma unroll
  for (int b = 0; b < GB; b++) acc[b] = 0.f;
  for (int k = k0; k < k1; k++) {
    float w = W[k * 128 + j];
    #pragma unroll
    for (int b = 0; b < GB; b++) acc[b] += md[b * FC1K + k] * w;
  }
  for (int b = 0; b < GB; b++) part[(c * GB + b) * 128 + j] = acc[b];
}

__global__ void k_fc1_reduce(const float* __restrict__ part, const float* __restrict__ bias,
                             float* __restrict__ out) {
  int b = blockIdx.x, j = threadIdx.x;
  float acc = 0.f;
  for (int c = 0; c < FC1CH; c++) acc += part[(c * GB + b) * 128 + j];
  out[b * 128 + j] = fmaxf(acc + bias[j], 0.f);
}

// ---------------- generic small dense: one block per row ----------------
__global__ void k_dense(const float* __restrict__ in, const float* __restrict__ W,
                        const float* __restrict__ bias, float* __restrict__ out,
                        int K, int J) {
  __shared__ float row[512];
  int b = blockIdx.x, j = threadIdx.x;
  for (int k = j; k < K; k += blockDim.x) row[k] = in[b * K + k];
  __syncthreads();
  float acc = 0.f;
  for (int k = 0; k < K; k++) acc += row[k] * W[k * J + j];
  out[b * J + j] = fmaxf(acc + bias[j], 0.f);
}

// fcc: concat([mp128, mm64, hp128, hm128]) @ W[448,128] + b, relu
__global__ void k_fcc(const float* __restrict__ mp, const float* __restrict__ mm,
                      const float* __restrict__ hp, const float* __restrict__ hm,
                      const float* __restrict__ W, const float* __restrict__ bias,
                      float* __restrict__ out) {
  __shared__ float row[448];
  int b = blockIdx.x, j = threadIdx.x;  // 128 threads
  row[j] = mp[b * 128 + j];
  if (j < 64) row[128 + j] = mm[b * 64 + j];
  row[192 + j] = hp[b * 128 + j];
  row[320 + j] = hm[b * 128 + j];
  __syncthreads();
  float acc = 0.f;
  #pragma unroll 4
  for (int k = 0; k < 448; k++) acc += row[k] * W[k * 128 + j];
  out[b * 128 + j] = fmaxf(acc + bias[j], 0.f);
}

// final: [64,128]@[128,2] + b, relu -> d_out
__global__ void k_final(const float* __restrict__ in, const float* __restrict__ W,
                        const float* __restrict__ bias, float* __restrict__ out) {
  int tid = threadIdx.x;
  if (tid >= 128) return;
  int b = tid >> 1, o = tid & 1;
  float acc = 0.f;
  for (int k = 0; k < 128; k++) acc += in[b * 128 + k] * W[k * 2 + o];
  out[b * 2 + o] = fmaxf(acc + bias[o], 0.f);
}

// ---------------- host ----------------
extern "C" void kernel_launch(void* const* d_in, const int* in_sizes, int n_in,
                              void* d_out, int out_size, void* d_ws, size_t ws_size,
                              hipStream_t stream) {
  const float* md_prot = (const float*)d_in[0];
  const float* md_mol  = (const float*)d_in[1];
  const float* x_prot  = (const float*)d_in[2];
  const float* x_mol   = (const float*)d_in[3];
  const int*   ei_p    = (const int*)d_in[4];
  const int*   bv_p    = (const int*)d_in[5];
  const int*   ei_m    = (const int*)d_in[6];
  const int*   bv_m    = (const int*)d_in[7];
  const float* fc1_w = (const float*)d_in[8],  * fc1_b = (const float*)d_in[9];
  const float* fc2_w = (const float*)d_in[10], * fc2_b = (const float*)d_in[11];
  const float* fcm1_w= (const float*)d_in[12], * fcm1_b= (const float*)d_in[13];
  const float* fcm2_w= (const float*)d_in[14], * fcm2_b= (const float*)d_in[15];
  const float* gp1_w = (const float*)d_in[16], * gp1_b = (const float*)d_in[17];
  const float* gp2_w = (const float*)d_in[18], * gp2_b = (const float*)d_in[19];
  const float* gm1_w = (const float*)d_in[20], * gm1_b = (const float*)d_in[21];
  const float* gm2_w = (const float*)d_in[22], * gm2_b = (const float*)d_in[23];
  const float* fcc_w = (const float*)d_in[24], * fcc_b = (const float*)d_in[25];
  const float* out_w = (const float*)d_in[26], * out_b = (const float*)d_in[27];

  const int NP = in_sizes[2] / 9;   // 100000
  const int EP = in_sizes[4] / 2;   // 1600000
  const int NM = in_sizes[3] / 9;   // 4096
  const int EM = in_sizes[6] / 2;   // 16384

  // workspace layout
  char* w = (char*)d_ws;
  size_t off = 0;
  auto take = [&](size_t bytes) -> void* {
    void* p = w + off;
    off = (off + bytes + 255) & ~(size_t)255;
    return p;
  };
  float* pA     = (float*)take((size_t)NP * 128 * 4);
  float* pB     = (float*)take((size_t)NP * 128 * 4);
  int*   idx_p  = (int*)  take((size_t)NP * CAP * 4);
  int*   cnt_p  = (int*)  take((size_t)NP * 4);
  float* dinv_p = (float*)take((size_t)NP * 4);
  float* mA     = (float*)take((size_t)NM * 128 * 4);
  float* mB     = (float*)take((size_t)NM * 128 * 4);
  int*   idx_m  = (int*)  take((size_t)NM * CAP * 4);
  int*   cnt_m  = (int*)  take((size_t)NM * 4);
  float* dinv_m = (float*)take((size_t)NM * 4);
  float* part   = (float*)take((size_t)FC1CH * GB * 128 * 4);
  float* mp1    = (float*)take(GB * 128 * 4);
  float* mp     = (float*)take(GB * 128 * 4);
  float* mm1    = (float*)take(GB * 64 * 4);
  float* mm     = (float*)take(GB * 64 * 4);
  float* hp     = (float*)take(GB * 128 * 4);
  float* hm     = (float*)take(GB * 128 * 4);
  float* cntp   = (float*)take(GB * 4);
  float* cntm   = (float*)take(GB * 4);
  float* fccout = (float*)take(GB * 128 * 4);
  (void)ws_size; (void)n_in; (void)out_size;

  // zero accumulators
  hipMemsetAsync(cnt_p, 0, (size_t)NP * 4, stream);
  hipMemsetAsync(cnt_m, 0, (size_t)NM * 4, stream);
  hipMemsetAsync(hp, 0, GB * 128 * 4, stream);
  hipMemsetAsync(hm, 0, GB * 128 * 4, stream);
  hipMemsetAsync(cntp, 0, GB * 4, stream);
  hipMemsetAsync(cntm, 0, GB * 4, stream);

  // ---- protein graph build ----
  k_bucket_fill<<<cdiv(EP, 256), 256, 0, stream>>>(ei_p, EP, cnt_p, idx_p);
  k_dinv<<<cdiv(NP, 256), 256, 0, stream>>>(cnt_p, dinv_p, NP);
  // ---- mol graph build ----
  k_bucket_fill<<<cdiv(EM, 256), 256, 0, stream>>>(ei_m, EM, cnt_m, idx_m);
  k_dinv<<<cdiv(NM, 256), 256, 0, stream>>>(cnt_m, dinv_m, NM);

  // ---- protein GCN ----
  k_lin9<<<cdiv((long)NP * 128, 256), 256, 0, stream>>>(x_prot, gp1_w, pA, NP);
  k_gather<<<NP, 128, 0, stream>>>(pA, dinv_p, cnt_p, idx_p, gp1_b, pB, NP);
  k_lin128<<<cdiv(NP, 16), 256, 0, stream>>>(pB, gp2_w, pA, NP);
  k_gather<<<NP, 128, 0, stream>>>(pA, dinv_p, cnt_p, idx_p, gp2_b, pB, NP);
  k_pool<<<cdiv(NP, 512), 128, 0, stream>>>(pB, bv_p, hp, NP, 512);
  k_count<<<cdiv(NP, 256), 256, 0, stream>>>(bv_p, cntp, NP);
  k_pool_div<<<cdiv(GB * 128, 256), 256, 0, stream>>>(hp, cntp, GB * 128);

  // ---- mol GCN ----
  k_lin9<<<cdiv((long)NM * 128, 256), 256, 0, stream>>>(x_mol, gm1_w, mA, NM);
  k_gather<<<NM, 128, 0, stream>>>(mA, dinv_m, cnt_m, idx_m, gm1_b, mB, NM);
  k_lin128<<<cdiv(NM, 16), 256, 0, stream>>>(mB, gm2_w, mA, NM);
  k_gather<<<NM, 128, 0, stream>>>(mA, dinv_m, cnt_m, idx_m, gm2_b, mB, NM);
  k_pool<<<cdiv(NM, 512), 128, 0, stream>>>(mB, bv_m, hm, NM, 512);
  k_count<<<cdiv(NM, 256), 256, 0, stream>>>(bv_m, cntm, NM);
  k_pool_div<<<cdiv(GB * 128, 256), 256, 0, stream>>>(hm, cntm, GB * 128);

  // ---- metadata MLPs ----
  k_fc1_part<<<FC1CH, 128, 0, stream>>>(md_prot, fc1_w, part);
  k_fc1_reduce<<<GB, 128, 0, stream>>>(part, fc1_b, mp1);
  k_dense<<<GB, 128, 0, stream>>>(mp1, fc2_w, fc2_b, mp, 128, 128);
  k_dense<<<GB, 64, 0, stream>>>(md_mol, fcm1_w, fcm1_b, mm1, 21, 64);
  k_dense<<<GB, 64, 0, stream>>>(mm1, fcm2_w, fcm2_b, mm, 64, 64);

  // ---- head ----
  k_fcc<<<GB, 128, 0, stream>>>(mp, mm, hp, hm, fcc_w, fcc_b, fccout);
  k_final<<<1, 128, 0, stream>>>(fccout, out_w, out_b, (float*)d_out);
}

// Round 2
// 1220.249 us; speedup vs baseline: 1.5343x; 1.5343x over previous
//
#include <hip/hip_runtime.h>

// ---------------- config ----------------
#define CAP 64          // per-node incoming-edge bucket capacity (max in-degree ~40)
#define GB  64          // batch (number of graphs)
#define F   128         // GCN hidden dim
#define FC1K 18640
#define FC1CH 128       // k-chunks for fc1
#define FC1CS 146       // ceil(18640/128)

static inline int cdiv(long a, long b){ return (int)((a + b - 1) / b); }

// ---------------- graph build ----------------
__global__ void k_bucket_fill(const int* __restrict__ ei, int E,
                              int* __restrict__ cnt, int* __restrict__ idx) {
  int e = blockIdx.x * blockDim.x + threadIdx.x;
  if (e >= E) return;
  int s = ei[e], d = ei[E + e];
  int c = atomicAdd(&cnt[d], 1);
  if (c < CAP) idx[d * CAP + c] = s;
}

__global__ void k_dinv(const int* __restrict__ cnt, float* __restrict__ dinv, int n) {
  int i = blockIdx.x * blockDim.x + threadIdx.x;
  if (i < n) dinv[i] = rsqrtf((float)cnt[i] + 1.0f);   // +1 self loop; deg >= 1
}

// per-graph node counts via binary search over the SORTED batch vector (no atomics)
__global__ void k_seg_counts(const int* __restrict__ batch, float* __restrict__ cnt, int n) {
  int b = threadIdx.x;
  if (b >= GB) return;
  int lo = 0, hi = n;
  while (lo < hi) { int mid = (lo + hi) >> 1; if (batch[mid] < b) lo = mid + 1; else hi = mid; }
  int start = lo;
  lo = 0; hi = n;
  while (lo < hi) { int mid = (lo + hi) >> 1; if (batch[mid] <= b) lo = mid + 1; else hi = mid; }
  cnt[b] = (float)(lo - start);
}

// ---------------- node linear layers ----------------
// x[n,9] @ W[9,128] -> h[n,128]
__global__ void k_lin9(const float* __restrict__ x, const float* __restrict__ W,
                       float* __restrict__ h, int n) {
  int t = blockIdx.x * blockDim.x + threadIdx.x;
  int v = t >> 7, j = t & 127;
  if (v >= n) return;
  float acc = 0.f;
  #pragma unroll
  for (int k = 0; k < 9; k++) acc += x[v * 9 + k] * W[k * 128 + j];
  h[v * 128 + j] = acc;
}

// h[n,128] @ W[128,128] -> out[n,128]; 16 nodes per 256-thread block
__global__ void k_lin128(const float* __restrict__ hin, const float* __restrict__ W,
                         float* __restrict__ hout, int n) {
  __shared__ float rows[16][128];
  int base = blockIdx.x * 16;
  int tid = threadIdx.x;
  for (int t = tid; t < 16 * 128; t += 256) {
    int v = base + (t >> 7);
    rows[t >> 7][t & 127] = (v < n) ? hin[v * 128 + (t & 127)] : 0.f;
  }
  __syncthreads();
  int j = tid & 127, s = tid >> 7;     // s in {0,1}
  float acc[8] = {0,0,0,0,0,0,0,0};
  for (int k = 0; k < 128; k++) {
    float w = W[k * 128 + j];
    #pragma unroll
    for (int r = 0; r < 8; r++) acc[r] += rows[s + 2 * r][k] * w;  // LDS broadcast
  }
  #pragma unroll
  for (int r = 0; r < 8; r++) {
    int v = base + s + 2 * r;
    if (v < n) hout[v * 128 + j] = acc[r];
  }
}

// ---------------- GCN aggregation (gather) + bias + relu ----------------
// out[v] = relu( dinv[v] * ( sum_{s in N(v)} dinv[s]*h[s] + dinv[v]*h[v] ) + b )
__global__ void k_gather(const float* __restrict__ h, const float* __restrict__ dinv,
                         const int* __restrict__ cnt, const int* __restrict__ idx,
                         const float* __restrict__ bias, float* __restrict__ out, int n) {
  int v = blockIdx.x;
  if (v >= n) return;
  int f = threadIdx.x;
  float dv = dinv[v];
  int deg = cnt[v]; if (deg > CAP) deg = CAP;
  float acc = dv * h[v * 128 + f];
  for (int p = 0; p < deg; p++) {
    int s = idx[v * CAP + p];
    acc += dinv[s] * h[s * 128 + f];
  }
  out[v * 128 + f] = fmaxf(dv * acc + bias[f], 0.f);
}

// ---------------- mean pool (batch vector is sorted) ----------------
__global__ void k_pool(const float* __restrict__ h, const int* __restrict__ batch,
                       float* __restrict__ sums, int n, int npb) {
  int f = threadIdx.x;
  long v0 = (long)blockIdx.x * npb;
  if (v0 >= n) return;
  long v1 = v0 + npb; if (v1 > n) v1 = n;
  int cur = batch[v0];
  float acc = 0.f;
  for (long v = v0; v < v1; ++v) {
    int bv = batch[v];
    if (bv != cur) { atomicAdd(&sums[cur * 128 + f], acc); acc = 0.f; cur = bv; }
    acc += h[v * 128 + f];
  }
  atomicAdd(&sums[cur * 128 + f], acc);
}

__global__ void k_pool_div(float* __restrict__ sums, const float* __restrict__ cnt, int total) {
  int i = blockIdx.x * blockDim.x + threadIdx.x;
  if (i < total) sums[i] /= fmaxf(cnt[i >> 7], 1.f);
}

// ---------------- fc1: [64,18640]@[18640,128], k-chunked ----------------
__global__ void k_fc1_part(const float* __restrict__ md, const float* __restrict__ W,
                           float* __restrict__ part) {
  int c = blockIdx.x, j = threadIdx.x;
  int k0 = c * FC1CS, k1 = k0 + FC1CS; if (k1 > FC1K) k1 = FC1K;
  float acc[GB];
  #pragma unroll
  for (int b = 0; b < GB; b++) acc[b] = 0.f;
  for (int k = k0; k < k1; k++) {
    float w = W[k * 128 + j];
    #pragma unroll
    for (int b = 0; b < GB; b++) acc[b] += md[b * FC1K + k] * w;
  }
  for (int b = 0; b < GB; b++) part[(c * GB + b) * 128 + j] = acc[b];
}

__global__ void k_fc1_reduce(const float* __restrict__ part, const float* __restrict__ bias,
                             float* __restrict__ out) {
  int b = blockIdx.x, j = threadIdx.x;
  float acc = 0.f;
  for (int c = 0; c < FC1CH; c++) acc += part[(c * GB + b) * 128 + j];
  out[b * 128 + j] = fmaxf(acc + bias[j], 0.f);
}

// ---------------- generic small dense: one block per row ----------------
__global__ void k_dense(const float* __restrict__ in, const float* __restrict__ W,
                        const float* __restrict__ bias, float* __restrict__ out,
                        int K, int J) {
  __shared__ float row[512];
  int b = blockIdx.x, j = threadIdx.x;
  for (int k = j; k < K; k += blockDim.x) row[k] = in[b * K + k];
  __syncthreads();
  float acc = 0.f;
  for (int k = 0; k < K; k++) acc += row[k] * W[k * J + j];
  out[b * J + j] = fmaxf(acc + bias[j], 0.f);
}

// fcc: concat([mp128, mm64, hp128, hm128]) @ W[448,128] + b, relu
__global__ void k_fcc(const float* __restrict__ mp, const float* __restrict__ mm,
                      const float* __restrict__ hp, const float* __restrict__ hm,
                      const float* __restrict__ W, const float* __restrict__ bias,
                      float* __restrict__ out) {
  __shared__ float row[448];
  int b = blockIdx.x, j = threadIdx.x;  // 128 threads
  row[j] = mp[b * 128 + j];
  if (j < 64) row[128 + j] = mm[b * 64 + j];
  row[192 + j] = hp[b * 128 + j];
  row[320 + j] = hm[b * 128 + j];
  __syncthreads();
  float acc = 0.f;
  #pragma unroll 4
  for (int k = 0; k < 448; k++) acc += row[k] * W[k * 128 + j];
  out[b * 128 + j] = fmaxf(acc + bias[j], 0.f);
}

// final: [64,128]@[128,2] + b, relu -> d_out
__global__ void k_final(const float* __restrict__ in, const float* __restrict__ W,
                        const float* __restrict__ bias, float* __restrict__ out) {
  int tid = threadIdx.x;
  if (tid >= 128) return;
  int b = tid >> 1, o = tid & 1;
  float acc = 0.f;
  for (int k = 0; k < 128; k++) acc += in[b * 128 + k] * W[k * 2 + o];
  out[b * 2 + o] = fmaxf(acc + bias[o], 0.f);
}

// ---------------- host ----------------
extern "C" void kernel_launch(void* const* d_in, const int* in_sizes, int n_in,
                              void* d_out, int out_size, void* d_ws, size_t ws_size,
                              hipStream_t stream) {
  const float* md_prot = (const float*)d_in[0];
  const float* md_mol  = (const float*)d_in[1];
  const float* x_prot  = (const float*)d_in[2];
  const float* x_mol   = (const float*)d_in[3];
  const int*   ei_p    = (const int*)d_in[4];
  const int*   bv_p    = (const int*)d_in[5];
  const int*   ei_m    = (const int*)d_in[6];
  const int*   bv_m    = (const int*)d_in[7];
  const float* fc1_w = (const float*)d_in[8],  * fc1_b = (const float*)d_in[9];
  const float* fc2_w = (const float*)d_in[10], * fc2_b = (const float*)d_in[11];
  const float* fcm1_w= (const float*)d_in[12], * fcm1_b= (const float*)d_in[13];
  const float* fcm2_w= (const float*)d_in[14], * fcm2_b= (const float*)d_in[15];
  const float* gp1_w = (const float*)d_in[16], * gp1_b = (const float*)d_in[17];
  const float* gp2_w = (const float*)d_in[18], * gp2_b = (const float*)d_in[19];
  const float* gm1_w = (const float*)d_in[20], * gm1_b = (const float*)d_in[21];
  const float* gm2_w = (const float*)d_in[22], * gm2_b = (const float*)d_in[23];
  const float* fcc_w = (const float*)d_in[24], * fcc_b = (const float*)d_in[25];
  const float* out_w = (const float*)d_in[26], * out_b = (const float*)d_in[27];

  const int NP = in_sizes[2] / 9;   // 100000
  const int EP = in_sizes[4] / 2;   // 1600000
  const int NM = in_sizes[3] / 9;   // 4096
  const int EM = in_sizes[6] / 2;   // 16384

  // workspace layout
  char* w = (char*)d_ws;
  size_t off = 0;
  auto take = [&](size_t bytes) -> void* {
    void* p = w + off;
    off = (off + bytes + 255) & ~(size_t)255;
    return p;
  };
  float* pA     = (float*)take((size_t)NP * 128 * 4);
  float* pB     = (float*)take((size_t)NP * 128 * 4);
  int*   idx_p  = (int*)  take((size_t)NP * CAP * 4);
  int*   cnt_p  = (int*)  take((size_t)NP * 4);
  float* dinv_p = (float*)take((size_t)NP * 4);
  float* mA     = (float*)take((size_t)NM * 128 * 4);
  float* mB     = (float*)take((size_t)NM * 128 * 4);
  int*   idx_m  = (int*)  take((size_t)NM * CAP * 4);
  int*   cnt_m  = (int*)  take((size_t)NM * 4);
  float* dinv_m = (float*)take((size_t)NM * 4);
  float* part   = (float*)take((size_t)FC1CH * GB * 128 * 4);
  float* mp1    = (float*)take(GB * 128 * 4);
  float* mp     = (float*)take(GB * 128 * 4);
  float* mm1    = (float*)take(GB * 64 * 4);
  float* mm     = (float*)take(GB * 64 * 4);
  float* hp     = (float*)take(GB * 128 * 4);
  float* hm     = (float*)take(GB * 128 * 4);
  float* cntp   = (float*)take(GB * 4);
  float* cntm   = (float*)take(GB * 4);
  float* fccout = (float*)take(GB * 128 * 4);
  (void)ws_size; (void)n_in; (void)out_size;

  // zero accumulators
  hipMemsetAsync(cnt_p, 0, (size_t)NP * 4, stream);
  hipMemsetAsync(cnt_m, 0, (size_t)NM * 4, stream);
  hipMemsetAsync(hp, 0, GB * 128 * 4, stream);
  hipMemsetAsync(hm, 0, GB * 128 * 4, stream);

  // ---- protein graph build ----
  k_bucket_fill<<<cdiv(EP, 256), 256, 0, stream>>>(ei_p, EP, cnt_p, idx_p);
  k_dinv<<<cdiv(NP, 256), 256, 0, stream>>>(cnt_p, dinv_p, NP);
  // ---- mol graph build ----
  k_bucket_fill<<<cdiv(EM, 256), 256, 0, stream>>>(ei_m, EM, cnt_m, idx_m);
  k_dinv<<<cdiv(NM, 256), 256, 0, stream>>>(cnt_m, dinv_m, NM);

  // ---- per-graph node counts (sorted batch vector -> binary search) ----
  k_seg_counts<<<1, GB, 0, stream>>>(bv_p, cntp, NP);
  k_seg_counts<<<1, GB, 0, stream>>>(bv_m, cntm, NM);

  // ---- protein GCN ----
  k_lin9<<<cdiv((long)NP * 128, 256), 256, 0, stream>>>(x_prot, gp1_w, pA, NP);
  k_gather<<<NP, 128, 0, stream>>>(pA, dinv_p, cnt_p, idx_p, gp1_b, pB, NP);
  k_lin128<<<cdiv(NP, 16), 256, 0, stream>>>(pB, gp2_w, pA, NP);
  k_gather<<<NP, 128, 0, stream>>>(pA, dinv_p, cnt_p, idx_p, gp2_b, pB, NP);
  k_pool<<<cdiv(NP, 512), 128, 0, stream>>>(pB, bv_p, hp, NP, 512);
  k_pool_div<<<cdiv(GB * 128, 256), 256, 0, stream>>>(hp, cntp, GB * 128);

  // ---- mol GCN ----
  k_lin9<<<cdiv((long)NM * 128, 256), 256, 0, stream>>>(x_mol, gm1_w, mA, NM);
  k_gather<<<NM, 128, 0, stream>>>(mA, dinv_m, cnt_m, idx_m, gm1_b, mB, NM);
  k_lin128<<<cdiv(NM, 16), 256, 0, stream>>>(mB, gm2_w, mA, NM);
  k_gather<<<NM, 128, 0, stream>>>(mA, dinv_m, cnt_m, idx_m, gm2_b, mB, NM);
  k_pool<<<cdiv(NM, 512), 128, 0, stream>>>(mB, bv_m, hm, NM, 512);
  k_pool_div<<<cdiv(GB * 128, 256), 256, 0, stream>>>(hm, cntm, GB * 128);

  // ---- metadata MLPs ----
  k_fc1_part<<<FC1CH, 128, 0, stream>>>(md_prot, fc1_w, part);
  k_fc1_reduce<<<GB, 128, 0, stream>>>(part, fc1_b, mp1);
  k_dense<<<GB, 128, 0, stream>>>(mp1, fc2_w, fc2_b, mp, 128, 128);
  k_dense<<<GB, 64, 0, stream>>>(md_mol, fcm1_w, fcm1_b, mm1, 21, 64);
  k_dense<<<GB, 64, 0, stream>>>(mm1, fcm2_w, fcm2_b, mm, 64, 64);

  // ---- head ----
  k_fcc<<<GB, 128, 0, stream>>>(mp, mm, hp, hm, fcc_w, fcc_b, fccout);
  k_final<<<1, 128, 0, stream>>>(fccout, out_w, out_b, (float*)d_out);
}

// Round 3
// 1016.739 us; speedup vs baseline: 1.8414x; 1.2002x over previous
//
#include <hip/hip_runtime.h>

// ---------------- config ----------------
#define CAP 64          // per-node incoming-edge bucket capacity (max in-degree ~40)
#define GB  64          // batch (number of graphs)
#define F   128         // GCN hidden dim
#define FC1K 18640
#define CH 932          // k-chunks for fc1 (932*20 == 18640 exactly)
#define KS 20

static inline int cdiv(long a, long b){ return (int)((a + b - 1) / b); }

// ---------------- graph build ----------------
__global__ void k_bucket_fill(const int* __restrict__ ei, int E,
                              int* __restrict__ cnt, int* __restrict__ idx) {
  int e = blockIdx.x * blockDim.x + threadIdx.x;
  if (e >= E) return;
  int s = ei[e], d = ei[E + e];
  int c = atomicAdd(&cnt[d], 1);
  if (c < CAP) idx[d * CAP + c] = s;
}

__global__ void k_dinv(const int* __restrict__ cnt, float* __restrict__ dinv, int n) {
  int i = blockIdx.x * blockDim.x + threadIdx.x;
  if (i < n) dinv[i] = rsqrtf((float)cnt[i] + 1.0f);   // +1 self loop; deg >= 1
}

// per-graph node counts via binary search over the SORTED batch vector (no atomics)
__global__ void k_seg_counts(const int* __restrict__ batch, float* __restrict__ cnt, int n) {
  int b = threadIdx.x;
  if (b >= GB) return;
  int lo = 0, hi = n;
  while (lo < hi) { int mid = (lo + hi) >> 1; if (batch[mid] < b) lo = mid + 1; else hi = mid; }
  int start = lo;
  lo = 0; hi = n;
  while (lo < hi) { int mid = (lo + hi) >> 1; if (batch[mid] <= b) lo = mid + 1; else hi = mid; }
  cnt[b] = (float)(lo - start);
}

// ---------------- node linear layers ----------------
// x[n,9] @ W[9,128] -> h[n,128]
__global__ void k_lin9(const float* __restrict__ x, const float* __restrict__ W,
                       float* __restrict__ h, int n) {
  int t = blockIdx.x * blockDim.x + threadIdx.x;
  int v = t >> 7, j = t & 127;
  if (v >= n) return;
  float acc = 0.f;
  #pragma unroll
  for (int k = 0; k < 9; k++) acc += x[v * 9 + k] * W[k * 128 + j];
  h[v * 128 + j] = acc;
}

// h[n,128] @ W[128,128] -> out[n,128]; 16 nodes per 256-thread block
__global__ void k_lin128(const float* __restrict__ hin, const float* __restrict__ W,
                         float* __restrict__ hout, int n) {
  __shared__ float rows[16][128];
  int base = blockIdx.x * 16;
  int tid = threadIdx.x;
  for (int t = tid; t < 16 * 128; t += 256) {
    int v = base + (t >> 7);
    rows[t >> 7][t & 127] = (v < n) ? hin[v * 128 + (t & 127)] : 0.f;
  }
  __syncthreads();
  int j = tid & 127, s = tid >> 7;     // s in {0,1}
  float acc[8] = {0,0,0,0,0,0,0,0};
  for (int k = 0; k < 128; k++) {
    float w = W[k * 128 + j];
    #pragma unroll
    for (int r = 0; r < 8; r++) acc[r] += rows[s + 2 * r][k] * w;  // LDS broadcast
  }
  #pragma unroll
  for (int r = 0; r < 8; r++) {
    int v = base + s + 2 * r;
    if (v < n) hout[v * 128 + j] = acc[r];
  }
}

// ---------------- GCN aggregation (gather) + bias + relu ----------------
__global__ void k_gather(const float* __restrict__ h, const float* __restrict__ dinv,
                         const int* __restrict__ cnt, const int* __restrict__ idx,
                         const float* __restrict__ bias, float* __restrict__ out, int n) {
  int v = blockIdx.x;
  if (v >= n) return;
  int f = threadIdx.x;
  float dv = dinv[v];
  int deg = cnt[v]; if (deg > CAP) deg = CAP;
  float acc = dv * h[v * 128 + f];
  for (int p = 0; p < deg; p++) {
    int s = idx[v * CAP + p];
    acc += dinv[s] * h[s * 128 + f];
  }
  out[v * 128 + f] = fmaxf(dv * acc + bias[f], 0.f);
}

// ---------------- mean pool (batch vector is sorted) ----------------
__global__ void k_pool(const float* __restrict__ h, const int* __restrict__ batch,
                       float* __restrict__ sums, int n, int npb) {
  int f = threadIdx.x;
  long v0 = (long)blockIdx.x * npb;
  if (v0 >= n) return;
  long v1 = v0 + npb; if (v1 > n) v1 = n;
  int cur = batch[v0];
  float acc = 0.f;
  for (long v = v0; v < v1; ++v) {
    int bv = batch[v];
    if (bv != cur) { atomicAdd(&sums[cur * 128 + f], acc); acc = 0.f; cur = bv; }
    acc += h[v * 128 + f];
  }
  atomicAdd(&sums[cur * 128 + f], acc);
}

__global__ void k_pool_div(float* __restrict__ sums, const float* __restrict__ cnt, int total) {
  int i = blockIdx.x * blockDim.x + threadIdx.x;
  if (i < total) sums[i] /= fmaxf(cnt[i >> 7], 1.f);
}

// ---------------- fc1: [64,18640]@[18640,128], heavy split-K ----------------
// phase 1: one block per k-chunk of KS=20; 256 threads (2 b-groups x 128 j)
__global__ void k_fc1_part(const float* __restrict__ md, const float* __restrict__ W,
                           float* __restrict__ part) {
  __shared__ float smd[64][KS];
  int c = blockIdx.x;
  int k0 = c * KS;
  int tid = threadIdx.x;
  for (int t = tid; t < 64 * KS; t += 256) {
    int b = t / KS, k = t % KS;
    smd[b][k] = md[(size_t)b * FC1K + k0 + k];
  }
  __syncthreads();
  int j = tid & 127, bg = tid >> 7;    // bg in {0,1}
  float acc[32];
  #pragma unroll
  for (int i = 0; i < 32; i++) acc[i] = 0.f;
  for (int k = 0; k < KS; k++) {
    float w = W[(size_t)(k0 + k) * 128 + j];
    #pragma unroll
    for (int i = 0; i < 32; i++) acc[i] += smd[bg * 32 + i][k] * w;
  }
  float* dst = part + ((size_t)c * 64 + bg * 32) * 128 + j;
  #pragma unroll
  for (int i = 0; i < 32; i++) dst[(size_t)i * 128] = acc[i];
}

// phase 2: 64 blocks (one per batch row) x 1024 threads (8 chunk-groups x 128 j)
__global__ void k_fc1_reduce(const float* __restrict__ part, const float* __restrict__ bias,
                             float* __restrict__ out) {
  __shared__ float red[8][128];
  int b = blockIdx.x;
  int j = threadIdx.x & 127, cg = threadIdx.x >> 7;
  float acc = 0.f;
  for (int c = cg; c < CH; c += 8) acc += part[((size_t)c * 64 + b) * 128 + j];
  red[cg][j] = acc;
  __syncthreads();
  if (cg == 0) {
    float s = red[0][j] + red[1][j] + red[2][j] + red[3][j]
            + red[4][j] + red[5][j] + red[6][j] + red[7][j];
    out[b * 128 + j] = fmaxf(s + bias[j], 0.f);
  }
}

// ---------------- generic small dense: one block per row ----------------
__global__ void k_dense(const float* __restrict__ in, const float* __restrict__ W,
                        const float* __restrict__ bias, float* __restrict__ out,
                        int K, int J) {
  __shared__ float row[512];
  int b = blockIdx.x, j = threadIdx.x;
  for (int k = j; k < K; k += blockDim.x) row[k] = in[b * K + k];
  __syncthreads();
  float acc = 0.f;
  for (int k = 0; k < K; k++) acc += row[k] * W[k * J + j];
  out[b * J + j] = fmaxf(acc + bias[j], 0.f);
}

// fcc: concat([mp128, mm64, hp128, hm128]) @ W[448,128] + b, relu
__global__ void k_fcc(const float* __restrict__ mp, const float* __restrict__ mm,
                      const float* __restrict__ hp, const float* __restrict__ hm,
                      const float* __restrict__ W, const float* __restrict__ bias,
                      float* __restrict__ out) {
  __shared__ float row[448];
  int b = blockIdx.x, j = threadIdx.x;  // 128 threads
  row[j] = mp[b * 128 + j];
  if (j < 64) row[128 + j] = mm[b * 64 + j];
  row[192 + j] = hp[b * 128 + j];
  row[320 + j] = hm[b * 128 + j];
  __syncthreads();
  float acc = 0.f;
  #pragma unroll 4
  for (int k = 0; k < 448; k++) acc += row[k] * W[k * 128 + j];
  out[b * 128 + j] = fmaxf(acc + bias[j], 0.f);
}

// final: [64,128]@[128,2] + b, relu -> d_out
__global__ void k_final(const float* __restrict__ in, const float* __restrict__ W,
                        const float* __restrict__ bias, float* __restrict__ out) {
  int tid = threadIdx.x;
  if (tid >= 128) return;
  int b = tid >> 1, o = tid & 1;
  float acc = 0.f;
  for (int k = 0; k < 128; k++) acc += in[b * 128 + k] * W[k * 2 + o];
  out[b * 2 + o] = fmaxf(acc + bias[o], 0.f);
}

// ---------------- host ----------------
extern "C" void kernel_launch(void* const* d_in, const int* in_sizes, int n_in,
                              void* d_out, int out_size, void* d_ws, size_t ws_size,
                              hipStream_t stream) {
  const float* md_prot = (const float*)d_in[0];
  const float* md_mol  = (const float*)d_in[1];
  const float* x_prot  = (const float*)d_in[2];
  const float* x_mol   = (const float*)d_in[3];
  const int*   ei_p    = (const int*)d_in[4];
  const int*   bv_p    = (const int*)d_in[5];
  const int*   ei_m    = (const int*)d_in[6];
  const int*   bv_m    = (const int*)d_in[7];
  const float* fc1_w = (const float*)d_in[8],  * fc1_b = (const float*)d_in[9];
  const float* fc2_w = (const float*)d_in[10], * fc2_b = (const float*)d_in[11];
  const float* fcm1_w= (const float*)d_in[12], * fcm1_b= (const float*)d_in[13];
  const float* fcm2_w= (const float*)d_in[14], * fcm2_b= (const float*)d_in[15];
  const float* gp1_w = (const float*)d_in[16], * gp1_b = (const float*)d_in[17];
  const float* gp2_w = (const float*)d_in[18], * gp2_b = (const float*)d_in[19];
  const float* gm1_w = (const float*)d_in[20], * gm1_b = (const float*)d_in[21];
  const float* gm2_w = (const float*)d_in[22], * gm2_b = (const float*)d_in[23];
  const float* fcc_w = (const float*)d_in[24], * fcc_b = (const float*)d_in[25];
  const float* out_w = (const float*)d_in[26], * out_b = (const float*)d_in[27];

  const int NP = in_sizes[2] / 9;   // 100000
  const int EP = in_sizes[4] / 2;   // 1600000
  const int NM = in_sizes[3] / 9;   // 4096
  const int EM = in_sizes[6] / 2;   // 16384

  // workspace layout
  char* w = (char*)d_ws;
  size_t off = 0;
  auto take = [&](size_t bytes) -> void* {
    void* p = w + off;
    off = (off + bytes + 255) & ~(size_t)255;
    return p;
  };
  float* pA     = (float*)take((size_t)NP * 128 * 4);   // also fc1 partials scratch (30.5MB < 51.2MB)
  float* pB     = (float*)take((size_t)NP * 128 * 4);
  int*   idx_p  = (int*)  take((size_t)NP * CAP * 4);
  int*   cnt_p  = (int*)  take((size_t)NP * 4);
  float* dinv_p = (float*)take((size_t)NP * 4);
  float* mA     = (float*)take((size_t)NM * 128 * 4);
  float* mB     = (float*)take((size_t)NM * 128 * 4);
  int*   idx_m  = (int*)  take((size_t)NM * CAP * 4);
  int*   cnt_m  = (int*)  take((size_t)NM * 4);
  float* dinv_m = (float*)take((size_t)NM * 4);
  float* mp1    = (float*)take(GB * 128 * 4);
  float* mp     = (float*)take(GB * 128 * 4);
  float* mm1    = (float*)take(GB * 64 * 4);
  float* mm     = (float*)take(GB * 64 * 4);
  float* hp     = (float*)take(GB * 128 * 4);
  float* hm     = (float*)take(GB * 128 * 4);
  float* cntp   = (float*)take(GB * 4);
  float* cntm   = (float*)take(GB * 4);
  float* fccout = (float*)take(GB * 128 * 4);
  (void)ws_size; (void)n_in; (void)out_size;

  // zero accumulators
  hipMemsetAsync(cnt_p, 0, (size_t)NP * 4, stream);
  hipMemsetAsync(cnt_m, 0, (size_t)NM * 4, stream);
  hipMemsetAsync(hp, 0, GB * 128 * 4, stream);
  hipMemsetAsync(hm, 0, GB * 128 * 4, stream);

  // ---- fc1 (runs BEFORE protein GCN so it can borrow pA as partials scratch) ----
  float* part = pA;
  k_fc1_part<<<CH, 256, 0, stream>>>(md_prot, fc1_w, part);
  k_fc1_reduce<<<GB, 1024, 0, stream>>>(part, fc1_b, mp1);
  k_dense<<<GB, 128, 0, stream>>>(mp1, fc2_w, fc2_b, mp, 128, 128);
  k_dense<<<GB, 64, 0, stream>>>(md_mol, fcm1_w, fcm1_b, mm1, 21, 64);
  k_dense<<<GB, 64, 0, stream>>>(mm1, fcm2_w, fcm2_b, mm, 64, 64);

  // ---- protein graph build ----
  k_bucket_fill<<<cdiv(EP, 256), 256, 0, stream>>>(ei_p, EP, cnt_p, idx_p);
  k_dinv<<<cdiv(NP, 256), 256, 0, stream>>>(cnt_p, dinv_p, NP);
  // ---- mol graph build ----
  k_bucket_fill<<<cdiv(EM, 256), 256, 0, stream>>>(ei_m, EM, cnt_m, idx_m);
  k_dinv<<<cdiv(NM, 256), 256, 0, stream>>>(cnt_m, dinv_m, NM);

  // ---- per-graph node counts (sorted batch vector -> binary search) ----
  k_seg_counts<<<1, GB, 0, stream>>>(bv_p, cntp, NP);
  k_seg_counts<<<1, GB, 0, stream>>>(bv_m, cntm, NM);

  // ---- protein GCN ----
  k_lin9<<<cdiv((long)NP * 128, 256), 256, 0, stream>>>(x_prot, gp1_w, pA, NP);
  k_gather<<<NP, 128, 0, stream>>>(pA, dinv_p, cnt_p, idx_p, gp1_b, pB, NP);
  k_lin128<<<cdiv(NP, 16), 256, 0, stream>>>(pB, gp2_w, pA, NP);
  k_gather<<<NP, 128, 0, stream>>>(pA, dinv_p, cnt_p, idx_p, gp2_b, pB, NP);
  k_pool<<<cdiv(NP, 512), 128, 0, stream>>>(pB, bv_p, hp, NP, 512);
  k_pool_div<<<cdiv(GB * 128, 256), 256, 0, stream>>>(hp, cntp, GB * 128);

  // ---- mol GCN ----
  k_lin9<<<cdiv((long)NM * 128, 256), 256, 0, stream>>>(x_mol, gm1_w, mA, NM);
  k_gather<<<NM, 128, 0, stream>>>(mA, dinv_m, cnt_m, idx_m, gm1_b, mB, NM);
  k_lin128<<<cdiv(NM, 16), 256, 0, stream>>>(mB, gm2_w, mA, NM);
  k_gather<<<NM, 128, 0, stream>>>(mA, dinv_m, cnt_m, idx_m, gm2_b, mB, NM);
  k_pool<<<cdiv(NM, 512), 128, 0, stream>>>(mB, bv_m, hm, NM, 512);
  k_pool_div<<<cdiv(GB * 128, 256), 256, 0, stream>>>(hm, cntm, GB * 128);

  // ---- head ----
  k_fcc<<<GB, 128, 0, stream>>>(mp, mm, hp, hm, fcc_w, fcc_b, fccout);
  k_final<<<1, 128, 0, stream>>>(fccout, out_w, out_b, (float*)d_out);
}

// Round 4
// 892.682 us; speedup vs baseline: 2.0973x; 1.1390x over previous
//
#include <hip/hip_runtime.h>

// ---------------- config ----------------
#define CAP 64          // per-node incoming-edge bucket capacity (max in-degree ~40)
#define GB  64          // batch (number of graphs)
#define F   128         // GCN hidden dim
#define FC1K 18640
#define CH 932          // k-chunks for fc1 (932*20 == 18640 exactly)
#define KS 20

static inline int cdiv(long a, long b){ return (int)((a + b - 1) / b); }

// ---------------- graph build ----------------
__global__ void k_bucket_fill(const int* __restrict__ ei, int E,
                              int* __restrict__ cnt, int* __restrict__ idx) {
  int e = blockIdx.x * blockDim.x + threadIdx.x;
  if (e >= E) return;
  int s = ei[e], d = ei[E + e];
  int c = atomicAdd(&cnt[d], 1);
  if (c < CAP) idx[d * CAP + c] = s;
}

__global__ void k_dinv(const int* __restrict__ cnt, float* __restrict__ dinv, int n) {
  int i = blockIdx.x * blockDim.x + threadIdx.x;
  if (i < n) dinv[i] = rsqrtf((float)cnt[i] + 1.0f);   // +1 self loop; deg >= 1
}

// per-graph node counts via binary search over the SORTED batch vector (no atomics)
__global__ void k_seg_counts(const int* __restrict__ batch, float* __restrict__ cnt, int n) {
  int b = threadIdx.x;
  if (b >= GB) return;
  int lo = 0, hi = n;
  while (lo < hi) { int mid = (lo + hi) >> 1; if (batch[mid] < b) lo = mid + 1; else hi = mid; }
  int start = lo;
  lo = 0; hi = n;
  while (lo < hi) { int mid = (lo + hi) >> 1; if (batch[mid] <= b) lo = mid + 1; else hi = mid; }
  cnt[b] = (float)(lo - start);
}

// ---------------- layer-1 aggregation on RAW 9-dim features ----------------
// ax[v] = dinv[v] * ( dinv[v]*x[v] + sum_{s in N(v)} dinv[s]*x[s] )
// 16 threads per node, lanes 0..8 active; idx/dinv loads are wave-broadcast.
__global__ void k_gather9(const float* __restrict__ x, const float* __restrict__ dinv,
                          const int* __restrict__ cnt, const int* __restrict__ idx,
                          float* __restrict__ ax, int n) {
  int t = blockIdx.x * blockDim.x + threadIdx.x;
  int v = t >> 4, f = t & 15;
  if (v >= n || f >= 9) return;
  float dv = dinv[v];
  int deg = cnt[v]; if (deg > CAP) deg = CAP;
  float acc = dv * x[(size_t)v * 9 + f];
  for (int p = 0; p < deg; p++) {
    int s = idx[v * CAP + p];
    acc += dinv[s] * x[(size_t)s * 9 + f];
  }
  ax[(size_t)v * 9 + f] = dv * acc;
}

// ax[n,9] @ W[9,128] + b, relu -> h[n,128]   (follows aggregation now)
__global__ void k_lin9b(const float* __restrict__ ax, const float* __restrict__ W,
                        const float* __restrict__ bias, float* __restrict__ h, int n) {
  int t = blockIdx.x * blockDim.x + threadIdx.x;
  int v = t >> 7, j = t & 127;
  if (v >= n) return;
  float acc = bias[j];
  #pragma unroll
  for (int k = 0; k < 9; k++) acc += ax[(size_t)v * 9 + k] * W[k * 128 + j];
  h[(size_t)v * 128 + j] = fmaxf(acc, 0.f);
}

// h[n,128] @ W[128,128] -> out[n,128]; 16 nodes per 256-thread block
__global__ void k_lin128(const float* __restrict__ hin, const float* __restrict__ W,
                         float* __restrict__ hout, int n) {
  __shared__ float rows[16][128];
  int base = blockIdx.x * 16;
  int tid = threadIdx.x;
  for (int t = tid; t < 16 * 128; t += 256) {
    int v = base + (t >> 7);
    rows[t >> 7][t & 127] = (v < n) ? hin[(size_t)v * 128 + (t & 127)] : 0.f;
  }
  __syncthreads();
  int j = tid & 127, s = tid >> 7;     // s in {0,1}
  float acc[8] = {0,0,0,0,0,0,0,0};
  for (int k = 0; k < 128; k++) {
    float w = W[k * 128 + j];
    #pragma unroll
    for (int r = 0; r < 8; r++) acc[r] += rows[s + 2 * r][k] * w;  // LDS broadcast
  }
  #pragma unroll
  for (int r = 0; r < 8; r++) {
    int v = base + s + 2 * r;
    if (v < n) hout[(size_t)v * 128 + j] = acc[r];
  }
}

// ---------------- layer-2 GCN aggregation (gather 128-dim) + bias + relu ----
__global__ void k_gather(const float* __restrict__ h, const float* __restrict__ dinv,
                         const int* __restrict__ cnt, const int* __restrict__ idx,
                         const float* __restrict__ bias, float* __restrict__ out, int n) {
  int v = blockIdx.x;
  if (v >= n) return;
  int f = threadIdx.x;
  float dv = dinv[v];
  int deg = cnt[v]; if (deg > CAP) deg = CAP;
  float acc = dv * h[(size_t)v * 128 + f];
  for (int p = 0; p < deg; p++) {
    int s = idx[v * CAP + p];
    acc += dinv[s] * h[(size_t)s * 128 + f];
  }
  out[(size_t)v * 128 + f] = fmaxf(dv * acc + bias[f], 0.f);
}

// ---------------- mean pool (batch vector is sorted) ----------------
__global__ void k_pool(const float* __restrict__ h, const int* __restrict__ batch,
                       float* __restrict__ sums, int n, int npb) {
  int f = threadIdx.x;
  long v0 = (long)blockIdx.x * npb;
  if (v0 >= n) return;
  long v1 = v0 + npb; if (v1 > n) v1 = n;
  int cur = batch[v0];
  float acc = 0.f;
  for (long v = v0; v < v1; ++v) {
    int bv = batch[v];
    if (bv != cur) { atomicAdd(&sums[cur * 128 + f], acc); acc = 0.f; cur = bv; }
    acc += h[(size_t)v * 128 + f];
  }
  atomicAdd(&sums[cur * 128 + f], acc);
}

__global__ void k_pool_div(float* __restrict__ sums, const float* __restrict__ cnt, int total) {
  int i = blockIdx.x * blockDim.x + threadIdx.x;
  if (i < total) sums[i] /= fmaxf(cnt[i >> 7], 1.f);
}

// ---------------- fc1: [64,18640]@[18640,128], heavy split-K ----------------
__global__ void k_fc1_part(const float* __restrict__ md, const float* __restrict__ W,
                           float* __restrict__ part) {
  __shared__ float smd[64][KS];
  int c = blockIdx.x;
  int k0 = c * KS;
  int tid = threadIdx.x;
  for (int t = tid; t < 64 * KS; t += 256) {
    int b = t / KS, k = t % KS;
    smd[b][k] = md[(size_t)b * FC1K + k0 + k];
  }
  __syncthreads();
  int j = tid & 127, bg = tid >> 7;    // bg in {0,1}
  float acc[32];
  #pragma unroll
  for (int i = 0; i < 32; i++) acc[i] = 0.f;
  for (int k = 0; k < KS; k++) {
    float w = W[(size_t)(k0 + k) * 128 + j];
    #pragma unroll
    for (int i = 0; i < 32; i++) acc[i] += smd[bg * 32 + i][k] * w;
  }
  float* dst = part + ((size_t)c * 64 + bg * 32) * 128 + j;
  #pragma unroll
  for (int i = 0; i < 32; i++) dst[(size_t)i * 128] = acc[i];
}

__global__ void k_fc1_reduce(const float* __restrict__ part, const float* __restrict__ bias,
                             float* __restrict__ out) {
  __shared__ float red[8][128];
  int b = blockIdx.x;
  int j = threadIdx.x & 127, cg = threadIdx.x >> 7;
  float acc = 0.f;
  for (int c = cg; c < CH; c += 8) acc += part[((size_t)c * 64 + b) * 128 + j];
  red[cg][j] = acc;
  __syncthreads();
  if (cg == 0) {
    float s = red[0][j] + red[1][j] + red[2][j] + red[3][j]
            + red[4][j] + red[5][j] + red[6][j] + red[7][j];
    out[b * 128 + j] = fmaxf(s + bias[j], 0.f);
  }
}

// ---------------- generic small dense: one block per row ----------------
__global__ void k_dense(const float* __restrict__ in, const float* __restrict__ W,
                        const float* __restrict__ bias, float* __restrict__ out,
                        int K, int J) {
  __shared__ float row[512];
  int b = blockIdx.x, j = threadIdx.x;
  for (int k = j; k < K; k += blockDim.x) row[k] = in[b * K + k];
  __syncthreads();
  float acc = 0.f;
  for (int k = 0; k < K; k++) acc += row[k] * W[k * J + j];
  out[b * J + j] = fmaxf(acc + bias[j], 0.f);
}

// fcc: concat([mp128, mm64, hp128, hm128]) @ W[448,128] + b, relu
__global__ void k_fcc(const float* __restrict__ mp, const float* __restrict__ mm,
                      const float* __restrict__ hp, const float* __restrict__ hm,
                      const float* __restrict__ W, const float* __restrict__ bias,
                      float* __restrict__ out) {
  __shared__ float row[448];
  int b = blockIdx.x, j = threadIdx.x;  // 128 threads
  row[j] = mp[b * 128 + j];
  if (j < 64) row[128 + j] = mm[b * 64 + j];
  row[192 + j] = hp[b * 128 + j];
  row[320 + j] = hm[b * 128 + j];
  __syncthreads();
  float acc = 0.f;
  #pragma unroll 4
  for (int k = 0; k < 448; k++) acc += row[k] * W[k * 128 + j];
  out[b * 128 + j] = fmaxf(acc + bias[j], 0.f);
}

// final: [64,128]@[128,2] + b, relu -> d_out
__global__ void k_final(const float* __restrict__ in, const float* __restrict__ W,
                        const float* __restrict__ bias, float* __restrict__ out) {
  int tid = threadIdx.x;
  if (tid >= 128) return;
  int b = tid >> 1, o = tid & 1;
  float acc = 0.f;
  for (int k = 0; k < 128; k++) acc += in[b * 128 + k] * W[k * 2 + o];
  out[b * 2 + o] = fmaxf(acc + bias[o], 0.f);
}

// ---------------- host ----------------
extern "C" void kernel_launch(void* const* d_in, const int* in_sizes, int n_in,
                              void* d_out, int out_size, void* d_ws, size_t ws_size,
                              hipStream_t stream) {
  const float* md_prot = (const float*)d_in[0];
  const float* md_mol  = (const float*)d_in[1];
  const float* x_prot  = (const float*)d_in[2];
  const float* x_mol   = (const float*)d_in[3];
  const int*   ei_p    = (const int*)d_in[4];
  const int*   bv_p    = (const int*)d_in[5];
  const int*   ei_m    = (const int*)d_in[6];
  const int*   bv_m    = (const int*)d_in[7];
  const float* fc1_w = (const float*)d_in[8],  * fc1_b = (const float*)d_in[9];
  const float* fc2_w = (const float*)d_in[10], * fc2_b = (const float*)d_in[11];
  const float* fcm1_w= (const float*)d_in[12], * fcm1_b= (const float*)d_in[13];
  const float* fcm2_w= (const float*)d_in[14], * fcm2_b= (const float*)d_in[15];
  const float* gp1_w = (const float*)d_in[16], * gp1_b = (const float*)d_in[17];
  const float* gp2_w = (const float*)d_in[18], * gp2_b = (const float*)d_in[19];
  const float* gm1_w = (const float*)d_in[20], * gm1_b = (const float*)d_in[21];
  const float* gm2_w = (const float*)d_in[22], * gm2_b = (const float*)d_in[23];
  const float* fcc_w = (const float*)d_in[24], * fcc_b = (const float*)d_in[25];
  const float* out_w = (const float*)d_in[26], * out_b = (const float*)d_in[27];

  const int NP = in_sizes[2] / 9;   // 100000
  const int EP = in_sizes[4] / 2;   // 1600000
  const int NM = in_sizes[3] / 9;   // 4096
  const int EM = in_sizes[6] / 2;   // 16384

  // workspace layout
  char* w = (char*)d_ws;
  size_t off = 0;
  auto take = [&](size_t bytes) -> void* {
    void* p = w + off;
    off = (off + bytes + 255) & ~(size_t)255;
    return p;
  };
  float* pA     = (float*)take((size_t)NP * 128 * 4);   // also fc1 partials scratch (30.5MB < 51.2MB)
  float* pB     = (float*)take((size_t)NP * 128 * 4);
  int*   idx_p  = (int*)  take((size_t)NP * CAP * 4);
  int*   cnt_p  = (int*)  take((size_t)NP * 4);
  float* dinv_p = (float*)take((size_t)NP * 4);
  float* axp    = (float*)take((size_t)NP * 9 * 4);
  float* mA     = (float*)take((size_t)NM * 128 * 4);
  float* mB     = (float*)take((size_t)NM * 128 * 4);
  int*   idx_m  = (int*)  take((size_t)NM * CAP * 4);
  int*   cnt_m  = (int*)  take((size_t)NM * 4);
  float* dinv_m = (float*)take((size_t)NM * 4);
  float* axm    = (float*)take((size_t)NM * 9 * 4);
  float* mp1    = (float*)take(GB * 128 * 4);
  float* mp     = (float*)take(GB * 128 * 4);
  float* mm1    = (float*)take(GB * 64 * 4);
  float* mm     = (float*)take(GB * 64 * 4);
  float* hp     = (float*)take(GB * 128 * 4);
  float* hm     = (float*)take(GB * 128 * 4);
  float* cntp   = (float*)take(GB * 4);
  float* cntm   = (float*)take(GB * 4);
  float* fccout = (float*)take(GB * 128 * 4);
  (void)ws_size; (void)n_in; (void)out_size;

  // zero accumulators
  hipMemsetAsync(cnt_p, 0, (size_t)NP * 4, stream);
  hipMemsetAsync(cnt_m, 0, (size_t)NM * 4, stream);
  hipMemsetAsync(hp, 0, GB * 128 * 4, stream);
  hipMemsetAsync(hm, 0, GB * 128 * 4, stream);

  // ---- fc1 (runs BEFORE protein GCN so it can borrow pA as partials scratch) ----
  float* part = pA;
  k_fc1_part<<<CH, 256, 0, stream>>>(md_prot, fc1_w, part);
  k_fc1_reduce<<<GB, 1024, 0, stream>>>(part, fc1_b, mp1);
  k_dense<<<GB, 128, 0, stream>>>(mp1, fc2_w, fc2_b, mp, 128, 128);
  k_dense<<<GB, 64, 0, stream>>>(md_mol, fcm1_w, fcm1_b, mm1, 21, 64);
  k_dense<<<GB, 64, 0, stream>>>(mm1, fcm2_w, fcm2_b, mm, 64, 64);

  // ---- graph build ----
  k_bucket_fill<<<cdiv(EP, 256), 256, 0, stream>>>(ei_p, EP, cnt_p, idx_p);
  k_dinv<<<cdiv(NP, 256), 256, 0, stream>>>(cnt_p, dinv_p, NP);
  k_bucket_fill<<<cdiv(EM, 256), 256, 0, stream>>>(ei_m, EM, cnt_m, idx_m);
  k_dinv<<<cdiv(NM, 256), 256, 0, stream>>>(cnt_m, dinv_m, NM);

  // ---- per-graph node counts (sorted batch vector -> binary search) ----
  k_seg_counts<<<1, GB, 0, stream>>>(bv_p, cntp, NP);
  k_seg_counts<<<1, GB, 0, stream>>>(bv_m, cntm, NM);

  // ---- protein GCN ----
  // layer 1 commuted: aggregate raw 9-dim x, then (.)@W1 + b1, relu
  k_gather9<<<cdiv((long)NP * 16, 256), 256, 0, stream>>>(x_prot, dinv_p, cnt_p, idx_p, axp, NP);
  k_lin9b<<<cdiv((long)NP * 128, 256), 256, 0, stream>>>(axp, gp1_w, gp1_b, pB, NP);
  // layer 2: h1@W2 then aggregate 128-dim
  k_lin128<<<cdiv(NP, 16), 256, 0, stream>>>(pB, gp2_w, pA, NP);
  k_gather<<<NP, 128, 0, stream>>>(pA, dinv_p, cnt_p, idx_p, gp2_b, pB, NP);
  k_pool<<<cdiv(NP, 512), 128, 0, stream>>>(pB, bv_p, hp, NP, 512);
  k_pool_div<<<cdiv(GB * 128, 256), 256, 0, stream>>>(hp, cntp, GB * 128);

  // ---- mol GCN ----
  k_gather9<<<cdiv((long)NM * 16, 256), 256, 0, stream>>>(x_mol, dinv_m, cnt_m, idx_m, axm, NM);
  k_lin9b<<<cdiv((long)NM * 128, 256), 256, 0, stream>>>(axm, gm1_w, gm1_b, mB, NM);
  k_lin128<<<cdiv(NM, 16), 256, 0, stream>>>(mB, gm2_w, mA, NM);
  k_gather<<<NM, 128, 0, stream>>>(mA, dinv_m, cnt_m, idx_m, gm2_b, mB, NM);
  k_pool<<<cdiv(NM, 512), 128, 0, stream>>>(mB, bv_m, hm, NM, 512);
  k_pool_div<<<cdiv(GB * 128, 256), 256, 0, stream>>>(hm, cntm, GB * 128);

  // ---- head ----
  k_fcc<<<GB, 128, 0, stream>>>(mp, mm, hp, hm, fcc_w, fcc_b, fccout);
  k_final<<<1, 128, 0, stream>>>(fccout, out_w, out_b, (float*)d_out);
}

// Round 5
// 819.901 us; speedup vs baseline: 2.2835x; 1.0888x over previous
//
#include <hip/hip_runtime.h>

// ---------------- config ----------------
#define CAP 64          // per-node incoming-edge bucket capacity (max in-degree ~40)
#define GB  64          // batch (number of graphs)
#define F   128         // GCN hidden dim
#define FC1K 18640
#define CH 932          // k-chunks for fc1 (932*20 == 18640 exactly)
#define KS 20

static inline int cdiv(long a, long b){ return (int)((a + b - 1) / b); }

// bf16 pack/unpack helpers (RNE)
__device__ inline unsigned pack_bf2(float a, float b) {
  unsigned ua = __float_as_uint(a); ua += 0x7fffu + ((ua >> 16) & 1u);
  unsigned ub = __float_as_uint(b); ub += 0x7fffu + ((ub >> 16) & 1u);
  return (ua >> 16) | (ub & 0xffff0000u);
}

// ---------------- graph build ----------------
__global__ void k_bucket_fill(const int* __restrict__ ei, int E,
                              int* __restrict__ cnt, int* __restrict__ idx) {
  int e = blockIdx.x * blockDim.x + threadIdx.x;
  if (e >= E) return;
  int s = ei[e], d = ei[E + e];
  int c = atomicAdd(&cnt[d], 1);
  if (c < CAP) idx[d * CAP + c] = s;
}

__global__ void k_dinv(const int* __restrict__ cnt, float* __restrict__ dinv, int n) {
  int i = blockIdx.x * blockDim.x + threadIdx.x;
  if (i < n) dinv[i] = rsqrtf((float)cnt[i] + 1.0f);   // +1 self loop; deg >= 1
}

// per-graph node counts via binary search over the SORTED batch vector (no atomics)
__global__ void k_seg_counts(const int* __restrict__ batch, float* __restrict__ cnt, int n) {
  int b = threadIdx.x;
  if (b >= GB) return;
  int lo = 0, hi = n;
  while (lo < hi) { int mid = (lo + hi) >> 1; if (batch[mid] < b) lo = mid + 1; else hi = mid; }
  int start = lo;
  lo = 0; hi = n;
  while (lo < hi) { int mid = (lo + hi) >> 1; if (batch[mid] <= b) lo = mid + 1; else hi = mid; }
  cnt[b] = (float)(lo - start);
}

// ---------------- layer-1 aggregation on RAW 9-dim features ----------------
__global__ void k_gather9(const float* __restrict__ x, const float* __restrict__ dinv,
                          const int* __restrict__ cnt, const int* __restrict__ idx,
                          float* __restrict__ ax, int n) {
  int t = blockIdx.x * blockDim.x + threadIdx.x;
  int v = t >> 4, f = t & 15;
  if (v >= n || f >= 9) return;
  float dv = dinv[v];
  int deg = cnt[v]; if (deg > CAP) deg = CAP;
  float acc = dv * x[(size_t)v * 9 + f];
  for (int p = 0; p < deg; p++) {
    int s = idx[v * CAP + p];
    acc += dinv[s] * x[(size_t)s * 9 + f];
  }
  ax[(size_t)v * 9 + f] = dv * acc;
}

// ax[n,9] @ W[9,128] + b, relu -> h[n,128]
__global__ void k_lin9b(const float* __restrict__ ax, const float* __restrict__ W,
                        const float* __restrict__ bias, float* __restrict__ h, int n) {
  int t = blockIdx.x * blockDim.x + threadIdx.x;
  int v = t >> 7, j = t & 127;
  if (v >= n) return;
  float acc = bias[j];
  #pragma unroll
  for (int k = 0; k < 9; k++) acc += ax[(size_t)v * 9 + k] * W[k * 128 + j];
  h[(size_t)v * 128 + j] = fmaxf(acc, 0.f);
}

// h[n,128] @ W[128,128], scale by dinv[v], pack to bf16 pairs -> hout[n][64] (uint)
// 16 nodes per 256-thread block; thread = (node-group rg 0..3) x (feature pair j 0..63)
__global__ void k_lin128_bf(const float* __restrict__ hin, const float* __restrict__ W,
                            const float* __restrict__ dinv, unsigned* __restrict__ hout, int n) {
  __shared__ float rows[16][128];
  int base = blockIdx.x * 16;
  int tid = threadIdx.x;
  for (int t = tid; t < 16 * 128; t += 256) {
    int v = base + (t >> 7);
    rows[t >> 7][t & 127] = (v < n) ? hin[(size_t)v * 128 + (t & 127)] : 0.f;
  }
  __syncthreads();
  int j = tid & 63, rg = tid >> 6;   // rg in {0..3}, 4 nodes each
  float acc0[4] = {0,0,0,0}, acc1[4] = {0,0,0,0};
  for (int k = 0; k < 128; k++) {
    float2 w = *(const float2*)&W[k * 128 + 2 * j];
    #pragma unroll
    for (int r = 0; r < 4; r++) {
      float hv = rows[rg * 4 + r][k];   // wave-uniform -> LDS broadcast
      acc0[r] += hv * w.x;
      acc1[r] += hv * w.y;
    }
  }
  #pragma unroll
  for (int r = 0; r < 4; r++) {
    int v = base + rg * 4 + r;
    if (v < n) {
      float dv = dinv[v];
      hout[(size_t)v * 64 + j] = pack_bf2(dv * acc0[r], dv * acc1[r]);
    }
  }
}

// ---------------- layer-2 aggregation on bf16-packed pre-scaled h' ---------
// out[v] = relu( dinv[v] * ( h'[v] + sum_{s in N(v)} h'[s] ) + b ),  h' = dinv .* (h@W)
// one 64-lane wave per node; each lane owns one bf16 pair; edge loop 4-deep.
__global__ void k_gather_bf(const unsigned* __restrict__ hb, const float* __restrict__ dinv,
                            const int* __restrict__ cnt, const int* __restrict__ idx,
                            const float* __restrict__ bias, float* __restrict__ out, int n) {
  int t = blockIdx.x * blockDim.x + threadIdx.x;
  int v = t >> 6, f = t & 63;
  if (v >= n) return;
  float dv = dinv[v];
  int deg = cnt[v]; if (deg > CAP) deg = CAP;
  const int* idxv = idx + (size_t)v * CAP;
  unsigned u = hb[(size_t)v * 64 + f];
  float accL = __uint_as_float(u << 16);
  float accH = __uint_as_float(u & 0xffff0000u);
  int p = 0;
  for (; p + 4 <= deg; p += 4) {
    int s0 = idxv[p], s1 = idxv[p + 1], s2 = idxv[p + 2], s3 = idxv[p + 3];
    unsigned u0 = hb[(size_t)s0 * 64 + f];
    unsigned u1 = hb[(size_t)s1 * 64 + f];
    unsigned u2 = hb[(size_t)s2 * 64 + f];
    unsigned u3 = hb[(size_t)s3 * 64 + f];
    accL += __uint_as_float(u0 << 16); accH += __uint_as_float(u0 & 0xffff0000u);
    accL += __uint_as_float(u1 << 16); accH += __uint_as_float(u1 & 0xffff0000u);
    accL += __uint_as_float(u2 << 16); accH += __uint_as_float(u2 & 0xffff0000u);
    accL += __uint_as_float(u3 << 16); accH += __uint_as_float(u3 & 0xffff0000u);
  }
  for (; p < deg; p++) {
    int s = idxv[p];
    unsigned uu = hb[(size_t)s * 64 + f];
    accL += __uint_as_float(uu << 16); accH += __uint_as_float(uu & 0xffff0000u);
  }
  float2 b2 = *(const float2*)&bias[2 * f];
  float2 o;
  o.x = fmaxf(dv * accL + b2.x, 0.f);
  o.y = fmaxf(dv * accH + b2.y, 0.f);
  *(float2*)&out[(size_t)v * 128 + 2 * f] = o;
}

// ---------------- mean pool (batch vector is sorted) ----------------
__global__ void k_pool(const float* __restrict__ h, const int* __restrict__ batch,
                       float* __restrict__ sums, int n, int npb) {
  int f = threadIdx.x;
  long v0 = (long)blockIdx.x * npb;
  if (v0 >= n) return;
  long v1 = v0 + npb; if (v1 > n) v1 = n;
  int cur = batch[v0];
  float acc = 0.f;
  for (long v = v0; v < v1; ++v) {
    int bv = batch[v];
    if (bv != cur) { atomicAdd(&sums[cur * 128 + f], acc); acc = 0.f; cur = bv; }
    acc += h[(size_t)v * 128 + f];
  }
  atomicAdd(&sums[cur * 128 + f], acc);
}

__global__ void k_pool_div(float* __restrict__ sums, const float* __restrict__ cnt, int total) {
  int i = blockIdx.x * blockDim.x + threadIdx.x;
  if (i < total) sums[i] /= fmaxf(cnt[i >> 7], 1.f);
}

// ---------------- fc1: [64,18640]@[18640,128], heavy split-K ----------------
__global__ void k_fc1_part(const float* __restrict__ md, const float* __restrict__ W,
                           float* __restrict__ part) {
  __shared__ float smd[64][KS];
  int c = blockIdx.x;
  int k0 = c * KS;
  int tid = threadIdx.x;
  for (int t = tid; t < 64 * KS; t += 256) {
    int b = t / KS, k = t % KS;
    smd[b][k] = md[(size_t)b * FC1K + k0 + k];
  }
  __syncthreads();
  int j = tid & 127, bg = tid >> 7;    // bg in {0,1}
  float acc[32];
  #pragma unroll
  for (int i = 0; i < 32; i++) acc[i] = 0.f;
  for (int k = 0; k < KS; k++) {
    float w = W[(size_t)(k0 + k) * 128 + j];
    #pragma unroll
    for (int i = 0; i < 32; i++) acc[i] += smd[bg * 32 + i][k] * w;
  }
  float* dst = part + ((size_t)c * 64 + bg * 32) * 128 + j;
  #pragma unroll
  for (int i = 0; i < 32; i++) dst[(size_t)i * 128] = acc[i];
}

__global__ void k_fc1_reduce(const float* __restrict__ part, const float* __restrict__ bias,
                             float* __restrict__ out) {
  __shared__ float red[8][128];
  int b = blockIdx.x;
  int j = threadIdx.x & 127, cg = threadIdx.x >> 7;
  float acc = 0.f;
  for (int c = cg; c < CH; c += 8) acc += part[((size_t)c * 64 + b) * 128 + j];
  red[cg][j] = acc;
  __syncthreads();
  if (cg == 0) {
    float s = red[0][j] + red[1][j] + red[2][j] + red[3][j]
            + red[4][j] + red[5][j] + red[6][j] + red[7][j];
    out[b * 128 + j] = fmaxf(s + bias[j], 0.f);
  }
}

// ---------------- generic small dense: one block per row ----------------
__global__ void k_dense(const float* __restrict__ in, const float* __restrict__ W,
                        const float* __restrict__ bias, float* __restrict__ out,
                        int K, int J) {
  __shared__ float row[512];
  int b = blockIdx.x, j = threadIdx.x;
  for (int k = j; k < K; k += blockDim.x) row[k] = in[b * K + k];
  __syncthreads();
  float acc = 0.f;
  for (int k = 0; k < K; k++) acc += row[k] * W[k * J + j];
  out[b * J + j] = fmaxf(acc + bias[j], 0.f);
}

// fcc: concat([mp128, mm64, hp128, hm128]) @ W[448,128] + b, relu
__global__ void k_fcc(const float* __restrict__ mp, const float* __restrict__ mm,
                      const float* __restrict__ hp, const float* __restrict__ hm,
                      const float* __restrict__ W, const float* __restrict__ bias,
                      float* __restrict__ out) {
  __shared__ float row[448];
  int b = blockIdx.x, j = threadIdx.x;  // 128 threads
  row[j] = mp[b * 128 + j];
  if (j < 64) row[128 + j] = mm[b * 64 + j];
  row[192 + j] = hp[b * 128 + j];
  row[320 + j] = hm[b * 128 + j];
  __syncthreads();
  float acc = 0.f;
  #pragma unroll 4
  for (int k = 0; k < 448; k++) acc += row[k] * W[k * 128 + j];
  out[b * 128 + j] = fmaxf(acc + bias[j], 0.f);
}

// final: [64,128]@[128,2] + b, relu -> d_out
__global__ void k_final(const float* __restrict__ in, const float* __restrict__ W,
                        const float* __restrict__ bias, float* __restrict__ out) {
  int tid = threadIdx.x;
  if (tid >= 128) return;
  int b = tid >> 1, o = tid & 1;
  float acc = 0.f;
  for (int k = 0; k < 128; k++) acc += in[b * 128 + k] * W[k * 2 + o];
  out[b * 2 + o] = fmaxf(acc + bias[o], 0.f);
}

// ---------------- host ----------------
extern "C" void kernel_launch(void* const* d_in, const int* in_sizes, int n_in,
                              void* d_out, int out_size, void* d_ws, size_t ws_size,
                              hipStream_t stream) {
  const float* md_prot = (const float*)d_in[0];
  const float* md_mol  = (const float*)d_in[1];
  const float* x_prot  = (const float*)d_in[2];
  const float* x_mol   = (const float*)d_in[3];
  const int*   ei_p    = (const int*)d_in[4];
  const int*   bv_p    = (const int*)d_in[5];
  const int*   ei_m    = (const int*)d_in[6];
  const int*   bv_m    = (const int*)d_in[7];
  const float* fc1_w = (const float*)d_in[8],  * fc1_b = (const float*)d_in[9];
  const float* fc2_w = (const float*)d_in[10], * fc2_b = (const float*)d_in[11];
  const float* fcm1_w= (const float*)d_in[12], * fcm1_b= (const float*)d_in[13];
  const float* fcm2_w= (const float*)d_in[14], * fcm2_b= (const float*)d_in[15];
  const float* gp1_w = (const float*)d_in[16], * gp1_b = (const float*)d_in[17];
  const float* gp2_w = (const float*)d_in[18], * gp2_b = (const float*)d_in[19];
  const float* gm1_w = (const float*)d_in[20], * gm1_b = (const float*)d_in[21];
  const float* gm2_w = (const float*)d_in[22], * gm2_b = (const float*)d_in[23];
  const float* fcc_w = (const float*)d_in[24], * fcc_b = (const float*)d_in[25];
  const float* out_w = (const float*)d_in[26], * out_b = (const float*)d_in[27];

  const int NP = in_sizes[2] / 9;   // 100000
  const int EP = in_sizes[4] / 2;   // 1600000
  const int NM = in_sizes[3] / 9;   // 4096
  const int EM = in_sizes[6] / 2;   // 16384

  // workspace layout
  char* w = (char*)d_ws;
  size_t off = 0;
  auto take = [&](size_t bytes) -> void* {
    void* p = w + off;
    off = (off + bytes + 255) & ~(size_t)255;
    return p;
  };
  float*    pA     = (float*)take((size_t)NP * 128 * 4);  // fc1 partials / gather output
  float*    pB     = (float*)take((size_t)NP * 128 * 4);  // h1
  unsigned* hbf_p  = (unsigned*)take((size_t)NP * 64 * 4);
  int*      idx_p  = (int*)  take((size_t)NP * CAP * 4);
  int*      cnt_p  = (int*)  take((size_t)NP * 4);
  float*    dinv_p = (float*)take((size_t)NP * 4);
  float*    axp    = (float*)take((size_t)NP * 9 * 4);
  float*    mA     = (float*)take((size_t)NM * 128 * 4);
  float*    mB     = (float*)take((size_t)NM * 128 * 4);
  unsigned* hbf_m  = (unsigned*)take((size_t)NM * 64 * 4);
  int*      idx_m  = (int*)  take((size_t)NM * CAP * 4);
  int*      cnt_m  = (int*)  take((size_t)NM * 4);
  float*    dinv_m = (float*)take((size_t)NM * 4);
  float*    axm    = (float*)take((size_t)NM * 9 * 4);
  float*    mp1    = (float*)take(GB * 128 * 4);
  float*    mp     = (float*)take(GB * 128 * 4);
  float*    mm1    = (float*)take(GB * 64 * 4);
  float*    mm     = (float*)take(GB * 64 * 4);
  float*    hp     = (float*)take(GB * 128 * 4);
  float*    hm     = (float*)take(GB * 128 * 4);
  float*    cntp   = (float*)take(GB * 4);
  float*    cntm   = (float*)take(GB * 4);
  float*    fccout = (float*)take(GB * 128 * 4);
  (void)ws_size; (void)n_in; (void)out_size;

  // zero accumulators
  hipMemsetAsync(cnt_p, 0, (size_t)NP * 4, stream);
  hipMemsetAsync(cnt_m, 0, (size_t)NM * 4, stream);
  hipMemsetAsync(hp, 0, GB * 128 * 4, stream);
  hipMemsetAsync(hm, 0, GB * 128 * 4, stream);

  // ---- fc1 (runs BEFORE protein GCN so it can borrow pA as partials scratch) ----
  float* part = pA;
  k_fc1_part<<<CH, 256, 0, stream>>>(md_prot, fc1_w, part);
  k_fc1_reduce<<<GB, 1024, 0, stream>>>(part, fc1_b, mp1);
  k_dense<<<GB, 128, 0, stream>>>(mp1, fc2_w, fc2_b, mp, 128, 128);
  k_dense<<<GB, 64, 0, stream>>>(md_mol, fcm1_w, fcm1_b, mm1, 21, 64);
  k_dense<<<GB, 64, 0, stream>>>(mm1, fcm2_w, fcm2_b, mm, 64, 64);

  // ---- graph build ----
  k_bucket_fill<<<cdiv(EP, 256), 256, 0, stream>>>(ei_p, EP, cnt_p, idx_p);
  k_dinv<<<cdiv(NP, 256), 256, 0, stream>>>(cnt_p, dinv_p, NP);
  k_bucket_fill<<<cdiv(EM, 256), 256, 0, stream>>>(ei_m, EM, cnt_m, idx_m);
  k_dinv<<<cdiv(NM, 256), 256, 0, stream>>>(cnt_m, dinv_m, NM);

  // ---- per-graph node counts (sorted batch vector -> binary search) ----
  k_seg_counts<<<1, GB, 0, stream>>>(bv_p, cntp, NP);
  k_seg_counts<<<1, GB, 0, stream>>>(bv_m, cntm, NM);

  // ---- protein GCN ----
  k_gather9<<<cdiv((long)NP * 16, 256), 256, 0, stream>>>(x_prot, dinv_p, cnt_p, idx_p, axp, NP);
  k_lin9b<<<cdiv((long)NP * 128, 256), 256, 0, stream>>>(axp, gp1_w, gp1_b, pB, NP);
  k_lin128_bf<<<cdiv(NP, 16), 256, 0, stream>>>(pB, gp2_w, dinv_p, hbf_p, NP);
  k_gather_bf<<<cdiv((long)NP * 64, 256), 256, 0, stream>>>(hbf_p, dinv_p, cnt_p, idx_p, gp2_b, pA, NP);
  k_pool<<<cdiv(NP, 512), 128, 0, stream>>>(pA, bv_p, hp, NP, 512);
  k_pool_div<<<cdiv(GB * 128, 256), 256, 0, stream>>>(hp, cntp, GB * 128);

  // ---- mol GCN ----
  k_gather9<<<cdiv((long)NM * 16, 256), 256, 0, stream>>>(x_mol, dinv_m, cnt_m, idx_m, axm, NM);
  k_lin9b<<<cdiv((long)NM * 128, 256), 256, 0, stream>>>(axm, gm1_w, gm1_b, mB, NM);
  k_lin128_bf<<<cdiv(NM, 16), 256, 0, stream>>>(mB, gm2_w, dinv_m, hbf_m, NM);
  k_gather_bf<<<cdiv((long)NM * 64, 256), 256, 0, stream>>>(hbf_m, dinv_m, cnt_m, idx_m, gm2_b, mA, NM);
  k_pool<<<cdiv(NM, 512), 128, 0, stream>>>(mA, bv_m, hm, NM, 512);
  k_pool_div<<<cdiv(GB * 128, 256), 256, 0, stream>>>(hm, cntm, GB * 128);

  // ---- head ----
  k_fcc<<<GB, 128, 0, stream>>>(mp, mm, hp, hm, fcc_w, fcc_b, fccout);
  k_final<<<1, 128, 0, stream>>>(fccout, out_w, out_b, (float*)d_out);
}

// Round 6
// 571.578 us; speedup vs baseline: 3.2756x; 1.4345x over previous
//
#include <hip/hip_runtime.h>

// ---------------- config ----------------
#define CAP 64          // per-node incoming-edge bucket capacity (max in-degree ~40)
#define GB  64          // batch (number of graphs)
#define F   128         // GCN hidden dim
#define FC1K 18640
#define CH 932          // k-chunks for fc1 (932*20 == 18640 exactly)
#define KS 20

static inline int cdiv(long a, long b){ return (int)((a + b - 1) / b); }

// bf16 pack/unpack helpers (RNE)
__device__ inline unsigned pack_bf2(float a, float b) {
  unsigned ua = __float_as_uint(a); ua += 0x7fffu + ((ua >> 16) & 1u);
  unsigned ub = __float_as_uint(b); ub += 0x7fffu + ((ub >> 16) & 1u);
  return (ua >> 16) | (ub & 0xffff0000u);
}

// ---------------- graph build ----------------
__global__ void k_bucket_fill(const int* __restrict__ ei, int E,
                              int* __restrict__ cnt, int* __restrict__ idx) {
  int e = blockIdx.x * blockDim.x + threadIdx.x;
  if (e >= E) return;
  int s = ei[e], d = ei[E + e];
  int c = atomicAdd(&cnt[d], 1);
  if (c < CAP) idx[d * CAP + c] = s;
}

__global__ void k_dinv(const int* __restrict__ cnt, float* __restrict__ dinv, int n) {
  int i = blockIdx.x * blockDim.x + threadIdx.x;
  if (i < n) dinv[i] = rsqrtf((float)cnt[i] + 1.0f);   // +1 self loop; deg >= 1
}

// per-graph node counts via binary search over the SORTED batch vector (no atomics)
__global__ void k_seg_counts(const int* __restrict__ batch, float* __restrict__ cnt, int n) {
  int b = threadIdx.x;
  if (b >= GB) return;
  int lo = 0, hi = n;
  while (lo < hi) { int mid = (lo + hi) >> 1; if (batch[mid] < b) lo = mid + 1; else hi = mid; }
  int start = lo;
  lo = 0; hi = n;
  while (lo < hi) { int mid = (lo + hi) >> 1; if (batch[mid] <= b) lo = mid + 1; else hi = mid; }
  cnt[b] = (float)(lo - start);
}

// ---------------- layer-1 aggregation on RAW 9-dim features ----------------
__global__ void k_gather9(const float* __restrict__ x, const float* __restrict__ dinv,
                          const int* __restrict__ cnt, const int* __restrict__ idx,
                          float* __restrict__ ax, int n) {
  int t = blockIdx.x * blockDim.x + threadIdx.x;
  int v = t >> 4, f = t & 15;
  if (v >= n || f >= 9) return;
  float dv = dinv[v];
  int deg = cnt[v]; if (deg > CAP) deg = CAP;
  float acc = dv * x[(size_t)v * 9 + f];
  for (int p = 0; p < deg; p++) {
    int s = idx[v * CAP + p];
    acc += dinv[s] * x[(size_t)s * 9 + f];
  }
  ax[(size_t)v * 9 + f] = dv * acc;
}

// ax[n,9] @ W[9,128] + b, relu -> h[n,128]
__global__ void k_lin9b(const float* __restrict__ ax, const float* __restrict__ W,
                        const float* __restrict__ bias, float* __restrict__ h, int n) {
  int t = blockIdx.x * blockDim.x + threadIdx.x;
  int v = t >> 7, j = t & 127;
  if (v >= n) return;
  float acc = bias[j];
  #pragma unroll
  for (int k = 0; k < 9; k++) acc += ax[(size_t)v * 9 + k] * W[k * 128 + j];
  h[(size_t)v * 128 + j] = fmaxf(acc, 0.f);
}

// h[n,128] @ W[128,128], scale by dinv[v], pack to bf16 pairs -> hout[n][64] (uint)
__global__ void k_lin128_bf(const float* __restrict__ hin, const float* __restrict__ W,
                            const float* __restrict__ dinv, unsigned* __restrict__ hout, int n) {
  __shared__ float rows[16][128];
  int base = blockIdx.x * 16;
  int tid = threadIdx.x;
  for (int t = tid; t < 16 * 128; t += 256) {
    int v = base + (t >> 7);
    rows[t >> 7][t & 127] = (v < n) ? hin[(size_t)v * 128 + (t & 127)] : 0.f;
  }
  __syncthreads();
  int j = tid & 63, rg = tid >> 6;   // rg in {0..3}, 4 nodes each
  float acc0[4] = {0,0,0,0}, acc1[4] = {0,0,0,0};
  for (int k = 0; k < 128; k++) {
    float2 w = *(const float2*)&W[k * 128 + 2 * j];
    #pragma unroll
    for (int r = 0; r < 4; r++) {
      float hv = rows[rg * 4 + r][k];   // wave-uniform -> LDS broadcast
      acc0[r] += hv * w.x;
      acc1[r] += hv * w.y;
    }
  }
  #pragma unroll
  for (int r = 0; r < 4; r++) {
    int v = base + rg * 4 + r;
    if (v < n) {
      float dv = dinv[v];
      hout[(size_t)v * 64 + j] = pack_bf2(dv * acc0[r], dv * acc1[r]);
    }
  }
}

// ---------------- layer-2 aggregation on bf16-packed pre-scaled h' ---------
__global__ void k_gather_bf(const unsigned* __restrict__ hb, const float* __restrict__ dinv,
                            const int* __restrict__ cnt, const int* __restrict__ idx,
                            const float* __restrict__ bias, float* __restrict__ out, int n) {
  int t = blockIdx.x * blockDim.x + threadIdx.x;
  int v = t >> 6, f = t & 63;
  if (v >= n) return;
  float dv = dinv[v];
  int deg = cnt[v]; if (deg > CAP) deg = CAP;
  const int* idxv = idx + (size_t)v * CAP;
  unsigned u = hb[(size_t)v * 64 + f];
  float accL = __uint_as_float(u << 16);
  float accH = __uint_as_float(u & 0xffff0000u);
  int p = 0;
  for (; p + 4 <= deg; p += 4) {
    int s0 = idxv[p], s1 = idxv[p + 1], s2 = idxv[p + 2], s3 = idxv[p + 3];
    unsigned u0 = hb[(size_t)s0 * 64 + f];
    unsigned u1 = hb[(size_t)s1 * 64 + f];
    unsigned u2 = hb[(size_t)s2 * 64 + f];
    unsigned u3 = hb[(size_t)s3 * 64 + f];
    accL += __uint_as_float(u0 << 16); accH += __uint_as_float(u0 & 0xffff0000u);
    accL += __uint_as_float(u1 << 16); accH += __uint_as_float(u1 & 0xffff0000u);
    accL += __uint_as_float(u2 << 16); accH += __uint_as_float(u2 & 0xffff0000u);
    accL += __uint_as_float(u3 << 16); accH += __uint_as_float(u3 & 0xffff0000u);
  }
  for (; p < deg; p++) {
    int s = idxv[p];
    unsigned uu = hb[(size_t)s * 64 + f];
    accL += __uint_as_float(uu << 16); accH += __uint_as_float(uu & 0xffff0000u);
  }
  float2 b2 = *(const float2*)&bias[2 * f];
  float2 o;
  o.x = fmaxf(dv * accL + b2.x, 0.f);
  o.y = fmaxf(dv * accH + b2.y, 0.f);
  *(float2*)&out[(size_t)v * 128 + 2 * f] = o;
}

// ---------------- mean pool (batch vector is sorted) ----------------
// npb small (64) so the grid supplies enough waves to hide load latency.
__global__ void k_pool(const float* __restrict__ h, const int* __restrict__ batch,
                       float* __restrict__ sums, int n, int npb) {
  int f = threadIdx.x;
  long v0 = (long)blockIdx.x * npb;
  if (v0 >= n) return;
  long v1 = v0 + npb; if (v1 > n) v1 = n;
  int cur = batch[v0];
  float acc = 0.f;
  for (long v = v0; v < v1; ++v) {
    int bv = batch[v];
    if (bv != cur) { atomicAdd(&sums[cur * 128 + f], acc); acc = 0.f; cur = bv; }
    acc += h[(size_t)v * 128 + f];
  }
  atomicAdd(&sums[cur * 128 + f], acc);
}

__global__ void k_pool_div(float* __restrict__ sums, const float* __restrict__ cnt, int total) {
  int i = blockIdx.x * blockDim.x + threadIdx.x;
  if (i < total) sums[i] /= fmaxf(cnt[i >> 7], 1.f);
}

// ---------------- fc1: [64,18640]@[18640,128], heavy split-K ----------------
__global__ void k_fc1_part(const float* __restrict__ md, const float* __restrict__ W,
                           float* __restrict__ part) {
  __shared__ float smd[64][KS];
  int c = blockIdx.x;
  int k0 = c * KS;
  int tid = threadIdx.x;
  for (int t = tid; t < 64 * KS; t += 256) {
    int b = t / KS, k = t % KS;
    smd[b][k] = md[(size_t)b * FC1K + k0 + k];
  }
  __syncthreads();
  int j = tid & 127, bg = tid >> 7;    // bg in {0,1}
  float acc[32];
  #pragma unroll
  for (int i = 0; i < 32; i++) acc[i] = 0.f;
  for (int k = 0; k < KS; k++) {
    float w = W[(size_t)(k0 + k) * 128 + j];
    #pragma unroll
    for (int i = 0; i < 32; i++) acc[i] += smd[bg * 32 + i][k] * w;
  }
  float* dst = part + ((size_t)c * 64 + bg * 32) * 128 + j;
  #pragma unroll
  for (int i = 0; i < 32; i++) dst[(size_t)i * 128] = acc[i];
}

__global__ void k_fc1_reduce(const float* __restrict__ part, const float* __restrict__ bias,
                             float* __restrict__ out) {
  __shared__ float red[8][128];
  int b = blockIdx.x;
  int j = threadIdx.x & 127, cg = threadIdx.x >> 7;
  float acc = 0.f;
  for (int c = cg; c < CH; c += 8) acc += part[((size_t)c * 64 + b) * 128 + j];
  red[cg][j] = acc;
  __syncthreads();
  if (cg == 0) {
    float s = red[0][j] + red[1][j] + red[2][j] + red[3][j]
            + red[4][j] + red[5][j] + red[6][j] + red[7][j];
    out[b * 128 + j] = fmaxf(s + bias[j], 0.f);
  }
}

// ---------------- generic small dense: one block per row ----------------
__global__ void k_dense(const float* __restrict__ in, const float* __restrict__ W,
                        const float* __restrict__ bias, float* __restrict__ out,
                        int K, int J) {
  __shared__ float row[512];
  int b = blockIdx.x, j = threadIdx.x;
  for (int k = j; k < K; k += blockDim.x) row[k] = in[b * K + k];
  __syncthreads();
  float acc = 0.f;
  for (int k = 0; k < K; k++) acc += row[k] * W[k * J + j];
  out[b * J + j] = fmaxf(acc + bias[j], 0.f);
}

// fcc: concat([mp128, mm64, hp128, hm128]) @ W[448,128] + b, relu
__global__ void k_fcc(const float* __restrict__ mp, const float* __restrict__ mm,
                      const float* __restrict__ hp, const float* __restrict__ hm,
                      const float* __restrict__ W, const float* __restrict__ bias,
                      float* __restrict__ out) {
  __shared__ float row[448];
  int b = blockIdx.x, j = threadIdx.x;  // 128 threads
  row[j] = mp[b * 128 + j];
  if (j < 64) row[128 + j] = mm[b * 64 + j];
  row[192 + j] = hp[b * 128 + j];
  row[320 + j] = hm[b * 128 + j];
  __syncthreads();
  float acc = 0.f;
  #pragma unroll 4
  for (int k = 0; k < 448; k++) acc += row[k] * W[k * 128 + j];
  out[b * 128 + j] = fmaxf(acc + bias[j], 0.f);
}

// final: [64,128]@[128,2] + b, relu -> d_out
__global__ void k_final(const float* __restrict__ in, const float* __restrict__ W,
                        const float* __restrict__ bias, float* __restrict__ out) {
  int tid = threadIdx.x;
  if (tid >= 128) return;
  int b = tid >> 1, o = tid & 1;
  float acc = 0.f;
  for (int k = 0; k < 128; k++) acc += in[b * 128 + k] * W[k * 2 + o];
  out[b * 2 + o] = fmaxf(acc + bias[o], 0.f);
}

// ---------------- host ----------------
extern "C" void kernel_launch(void* const* d_in, const int* in_sizes, int n_in,
                              void* d_out, int out_size, void* d_ws, size_t ws_size,
                              hipStream_t stream) {
  const float* md_prot = (const float*)d_in[0];
  const float* md_mol  = (const float*)d_in[1];
  const float* x_prot  = (const float*)d_in[2];
  const float* x_mol   = (const float*)d_in[3];
  const int*   ei_p    = (const int*)d_in[4];
  const int*   bv_p    = (const int*)d_in[5];
  const int*   ei_m    = (const int*)d_in[6];
  const int*   bv_m    = (const int*)d_in[7];
  const float* fc1_w = (const float*)d_in[8],  * fc1_b = (const float*)d_in[9];
  const float* fc2_w = (const float*)d_in[10], * fc2_b = (const float*)d_in[11];
  const float* fcm1_w= (const float*)d_in[12], * fcm1_b= (const float*)d_in[13];
  const float* fcm2_w= (const float*)d_in[14], * fcm2_b= (const float*)d_in[15];
  const float* gp1_w = (const float*)d_in[16], * gp1_b = (const float*)d_in[17];
  const float* gp2_w = (const float*)d_in[18], * gp2_b = (const float*)d_in[19];
  const float* gm1_w = (const float*)d_in[20], * gm1_b = (const float*)d_in[21];
  const float* gm2_w = (const float*)d_in[22], * gm2_b = (const float*)d_in[23];
  const float* fcc_w = (const float*)d_in[24], * fcc_b = (const float*)d_in[25];
  const float* out_w = (const float*)d_in[26], * out_b = (const float*)d_in[27];

  const int NP = in_sizes[2] / 9;   // 100000
  const int EP = in_sizes[4] / 2;   // 1600000
  const int NM = in_sizes[3] / 9;   // 4096
  const int EM = in_sizes[6] / 2;   // 16384

  // workspace layout
  char* w = (char*)d_ws;
  size_t off = 0;
  auto take = [&](size_t bytes) -> void* {
    void* p = w + off;
    off = (off + bytes + 255) & ~(size_t)255;
    return p;
  };
  float*    pA     = (float*)take((size_t)NP * 128 * 4);  // fc1 partials / gather output
  float*    pB     = (float*)take((size_t)NP * 128 * 4);  // h1
  unsigned* hbf_p  = (unsigned*)take((size_t)NP * 64 * 4);
  int*      idx_p  = (int*)  take((size_t)NP * CAP * 4);
  int*      cnt_p  = (int*)  take((size_t)NP * 4);
  float*    dinv_p = (float*)take((size_t)NP * 4);
  float*    axp    = (float*)take((size_t)NP * 9 * 4);
  float*    mA     = (float*)take((size_t)NM * 128 * 4);
  float*    mB     = (float*)take((size_t)NM * 128 * 4);
  unsigned* hbf_m  = (unsigned*)take((size_t)NM * 64 * 4);
  int*      idx_m  = (int*)  take((size_t)NM * CAP * 4);
  int*      cnt_m  = (int*)  take((size_t)NM * 4);
  float*    dinv_m = (float*)take((size_t)NM * 4);
  float*    axm    = (float*)take((size_t)NM * 9 * 4);
  float*    mp1    = (float*)take(GB * 128 * 4);
  float*    mp     = (float*)take(GB * 128 * 4);
  float*    mm1    = (float*)take(GB * 64 * 4);
  float*    mm     = (float*)take(GB * 64 * 4);
  float*    hp     = (float*)take(GB * 128 * 4);
  float*    hm     = (float*)take(GB * 128 * 4);
  float*    cntp   = (float*)take(GB * 4);
  float*    cntm   = (float*)take(GB * 4);
  float*    fccout = (float*)take(GB * 128 * 4);
  (void)ws_size; (void)n_in; (void)out_size;

  // zero accumulators
  hipMemsetAsync(cnt_p, 0, (size_t)NP * 4, stream);
  hipMemsetAsync(cnt_m, 0, (size_t)NM * 4, stream);
  hipMemsetAsync(hp, 0, GB * 128 * 4, stream);
  hipMemsetAsync(hm, 0, GB * 128 * 4, stream);

  // ---- fc1 (runs BEFORE protein GCN so it can borrow pA as partials scratch) ----
  float* part = pA;
  k_fc1_part<<<CH, 256, 0, stream>>>(md_prot, fc1_w, part);
  k_fc1_reduce<<<GB, 1024, 0, stream>>>(part, fc1_b, mp1);
  k_dense<<<GB, 128, 0, stream>>>(mp1, fc2_w, fc2_b, mp, 128, 128);
  k_dense<<<GB, 64, 0, stream>>>(md_mol, fcm1_w, fcm1_b, mm1, 21, 64);
  k_dense<<<GB, 64, 0, stream>>>(mm1, fcm2_w, fcm2_b, mm, 64, 64);

  // ---- graph build ----
  k_bucket_fill<<<cdiv(EP, 256), 256, 0, stream>>>(ei_p, EP, cnt_p, idx_p);
  k_dinv<<<cdiv(NP, 256), 256, 0, stream>>>(cnt_p, dinv_p, NP);
  k_bucket_fill<<<cdiv(EM, 256), 256, 0, stream>>>(ei_m, EM, cnt_m, idx_m);
  k_dinv<<<cdiv(NM, 256), 256, 0, stream>>>(cnt_m, dinv_m, NM);

  // ---- per-graph node counts (sorted batch vector -> binary search) ----
  k_seg_counts<<<1, GB, 0, stream>>>(bv_p, cntp, NP);
  k_seg_counts<<<1, GB, 0, stream>>>(bv_m, cntm, NM);

  // ---- protein GCN ----
  k_gather9<<<cdiv((long)NP * 16, 256), 256, 0, stream>>>(x_prot, dinv_p, cnt_p, idx_p, axp, NP);
  k_lin9b<<<cdiv((long)NP * 128, 256), 256, 0, stream>>>(axp, gp1_w, gp1_b, pB, NP);
  k_lin128_bf<<<cdiv(NP, 16), 256, 0, stream>>>(pB, gp2_w, dinv_p, hbf_p, NP);
  k_gather_bf<<<cdiv((long)NP * 64, 256), 256, 0, stream>>>(hbf_p, dinv_p, cnt_p, idx_p, gp2_b, pA, NP);
  k_pool<<<cdiv(NP, 64), 128, 0, stream>>>(pA, bv_p, hp, NP, 64);
  k_pool_div<<<cdiv(GB * 128, 256), 256, 0, stream>>>(hp, cntp, GB * 128);

  // ---- mol GCN ----
  k_gather9<<<cdiv((long)NM * 16, 256), 256, 0, stream>>>(x_mol, dinv_m, cnt_m, idx_m, axm, NM);
  k_lin9b<<<cdiv((long)NM * 128, 256), 256, 0, stream>>>(axm, gm1_w, gm1_b, mB, NM);
  k_lin128_bf<<<cdiv(NM, 16), 256, 0, stream>>>(mB, gm2_w, dinv_m, hbf_m, NM);
  k_gather_bf<<<cdiv((long)NM * 64, 256), 256, 0, stream>>>(hbf_m, dinv_m, cnt_m, idx_m, gm2_b, mA, NM);
  k_pool<<<cdiv(NM, 64), 128, 0, stream>>>(mA, bv_m, hm, NM, 64);
  k_pool_div<<<cdiv(GB * 128, 256), 256, 0, stream>>>(hm, cntm, GB * 128);

  // ---- head ----
  k_fcc<<<GB, 128, 0, stream>>>(mp, mm, hp, hm, fcc_w, fcc_b, fccout);
  k_final<<<1, 128, 0, stream>>>(fccout, out_w, out_b, (float*)d_out);
}